// Round 8
// baseline (1311.724 us; speedup 1.0000x reference)
//
#include <hip/hip_runtime.h>
#include <math.h>

#define BB 32
#define HH_ 128
#define WW_ 256

typedef _Float16 f16_t;
typedef _Float16 half8 __attribute__((ext_vector_type(8)));
typedef _Float16 half4 __attribute__((ext_vector_type(4)));
typedef _Float16 half2v __attribute__((ext_vector_type(2)));
typedef float floatx4 __attribute__((ext_vector_type(4)));

// Branch-free fast gelu, relu-form (A-S 7.1.26, |erf err| <= 1.5e-7).
__device__ __forceinline__ float gelu_f(float v){
  float av = __builtin_fabsf(v);
  float s = av * 0.70710678118654752f;
  float k = __builtin_amdgcn_rcpf(__builtin_fmaf(0.3275911f, s, 1.0f));
  float p = __builtin_fmaf(1.061405429f, k, -1.453152027f);
  p = __builtin_fmaf(p, k, 1.421413741f);
  p = __builtin_fmaf(p, k, -0.284496736f);
  p = __builtin_fmaf(p, k, 0.254829592f);
  p = p * k;
  float e = __expf(-s * s);
  float q = 0.5f * av * p;
  return __builtin_fmaf(-q, e, fmaxf(v, 0.f));
}

// Exact-reduced DFT twiddle: angle = sgn * 2*pi * (prod mod N) / N.
__device__ __forceinline__ float2 twiddle(int prod, int N, float sgn){
  int m = prod & (N - 1);
  float a = sgn * (6.2831853071795864769f / (float)N) * (float)m;
  return make_float2(cosf(a), sinf(a));
}

__global__ void k_diag(float* out, float v){ out[threadIdx.x] = v; }

// ---- merged prep: [0,113) tables+head-f16; [113,169) wprep;
//      [169,937) mixprep; [937,1001) twA; [1001,1009) ext-MLP g vector -------
__global__ __launch_bounds__(256) void k_prep(
      float* gg, float2* thf, float2* thi, f16_t* twzh,
      const float* __restrict__ f1_w, const float* __restrict__ f2_w,
      const float* __restrict__ f3_w, f16_t* f1T, f16_t* f2T, f16_t* f3T,
      const float* __restrict__ tw, f16_t* __restrict__ wT,
      const float* __restrict__ w1r, const float* __restrict__ w1i,
      const float* __restrict__ w2r, const float* __restrict__ w2i,
      float2* __restrict__ wmix, f16_t* __restrict__ twA,
      const float* __restrict__ ext, const float* __restrict__ day_emb,
      const float* __restrict__ hour_emb, const float* __restrict__ e1_w,
      const float* __restrict__ e1_b){
  __shared__ __align__(16) char smp[53248];
  int blk = blockIdx.x, tid = threadIdx.x;
  if (blk < 113){
    int t = blk*256 + tid;
    if (t < 3072){
      // spare slot
    } else if (t < 6144){                // forward h-DFT: [h][j]
      int f = t-3072; int h = f/24, j = f%24;
      int kx = (j<12)? j : j+104;
      thf[f] = twiddle(h*kx, 128, -1.f);
    } else if (t < 9216){                // inverse h (includes 1/128)
      int f = t-6144; int h = f/24, j = f%24;
      int kx = (j<12)? j : j+104;
      float2 c = twiddle(h*kx, 128, 1.f);
      thi[f] = make_float2(c.x*0.0078125f, c.y*0.0078125f);
    } else if (t < 12288){               // inverse w (c2r) coefs, f16
      int f = t-9216; int w = f/12, ky = f%12;
      float2 c = twiddle(w*ky, 256, 1.f);
      float s = (ky==0)? 0.00390625f : 0.0078125f;   // (1 or 2)/256
      twzh[w*32 + ky]      = (f16_t)( s*c.x);
      twzh[w*32 + 12 + ky] = (f16_t)(-s*c.y);
      if (ky < 8) twzh[w*32 + 24 + ky] = (f16_t)0.f;
    } else {
      int t2 = t - 12288;                // head weights -> f16
      if (t2 < 8192) f1T[t2] = (f16_t)f1_w[t2];
      else if (t2 < 16384) f2T[t2-8192] = (f16_t)f2_w[t2-8192];
      else if (t2 < 16512) f3T[t2-16384] = (f16_t)f3_w[t2-16384];
    }
  } else if (blk < 169){                 // conv weight transpose via LDS
    float* s = (float*)smp;              // [o16][c][tap]
    int b2 = blk - 113;
    int og = b2 & 3, tt = b2 >> 2;
    const float* src = tw + (long)tt*36864 + og*9216;
    for (int f = tid; f < 9216; f += 256) s[f] = src[f];
    __syncthreads();
    for (int f = tid; f < 9216; f += 256){
      int c = f & 63; int r = f >> 6;
      int o16 = r % 16, tap = r / 16;
      float v = s[(o16*64 + c)*9 + tap];
      wT[(((long)tt*9 + tap)*64 + og*16 + o16)*64 + c] = (f16_t)v;
    }
  } else if (blk < 937){                 // spectral weight transpose via LDS
    float* sr = (float*)smp;             // 6656 f
    float* si = (float*)(smp + 26624);   // 6656 f
    int b2 = blk - 169;                  // < 768
    int ig  = b2 & 7;
    int kx  = (b2 >> 3) % 12;
    int sel = (b2 / 96) & 1;
    int l   = b2 / 192;
    const float* wr = sel ? w2r : w1r;
    const float* wi = sel ? w2i : w1i;
    for (int f = tid; f < 6144; f += 256){
      int i8 = f / 768; int rem = f % 768;
      int o = rem / 12, ky = rem % 12;
      long addr = (((long)l*64 + ig*8 + i8)*64 + o)*144 + kx*12 + ky;
      sr[(i8*64 + o)*13 + ky] = wr[addr];
      si[(i8*64 + o)*13 + ky] = wi[addr];
    }
    __syncthreads();
    int j = sel ? (kx + 12) : kx;
    for (int f = tid; f < 6144; f += 256){
      int o = f & 63; int r = f >> 6;
      int ky = r % 12, i8 = r / 12;
      int sidx = (i8*64 + o)*13 + ky;
      wmix[(((long)l*288 + j*12 + ky))*4096 + (ig*8 + i8)*64 + o] =
          make_float2(sr[sidx], si[sidx]);
    }
  } else if (blk < 1001){                // twA[half][hl][32 m][128 k] f16
    int t = (blk - 937)*256 + tid;       // < 16384
    int halfi = t >> 13, r = t & 8191;
    int hl = r >> 12, r2 = r & 4095;
    int m = r2 >> 7, k = r2 & 127;
    f16_t v = (f16_t)0.f;
    if (m < 24){
      int ky = m >> 1, ri = m & 1;
      int w = halfi*128 + k;
      float2 c = twiddle(w*ky, 256, -1.f);
      float t32 = ri ? c.y : c.x;
      f16_t hi = (f16_t)t32;
      v = hl ? (f16_t)(t32 - (float)hi) : hi;
    }
    twA[t] = v;
  } else {                               // ext MLP g: gg[32 b][64 j]
    int b2 = blk - 1001;                 // 0..7
    int bloc = tid >> 6, j = tid & 63;
    int b = b2*4 + bloc;
    const float* e = ext + b*6;
    float emb[6];
    emb[0] = e[0];
    int d  = (int)e[2];
    emb[1] = day_emb[d*2];  emb[2] = day_emb[d*2+1];
    int hr = (int)e[3];
    emb[3] = hour_emb[hr*3]; emb[4] = hour_emb[hr*3+1]; emb[5] = hour_emb[hr*3+2];
    float acc = e1_b[j];
    #pragma unroll
    for (int k = 0; k < 6; k++) acc += emb[k]*e1_w[j*6+k];
    gg[b*64 + j] = gelu_f(acc);
  }
}

// ---- gate precompute: gate[b][hw] = gelu(g[b] . e2_w[hw] + e2_b[hw]) --------
__global__ __launch_bounds__(256) void k_gate(const float* __restrict__ gg,
      const float* __restrict__ e2_w, const float* __restrict__ e2_b,
      float* __restrict__ gate){
  __shared__ float gs[2048];
  int tid = threadIdx.x;
  for (int f = tid; f < 2048; f += 256) gs[f] = gg[f];
  __syncthreads();
  long hw = (long)blockIdx.x*256 + tid;
  const float4* wrow = (const float4*)(e2_w + hw*64);
  float4 w[16];
  #pragma unroll
  for (int k = 0; k < 16; k++) w[k] = wrow[k];
  float eb2 = e2_b[hw];
  for (int b = 0; b < 32; b++){
    const float* g = gs + b*64;
    float acc = eb2;
    #pragma unroll
    for (int k = 0; k < 16; k++){
      float4 v = w[k];
      acc += v.x*g[4*k] + v.y*g[4*k+1] + v.z*g[4*k+2] + v.w*g[4*k+3];
    }
    gate[(long)b*32768 + hw] = gelu_f(acc);
  }
}

// ---- encoder + layer-0 w-DFT (MFMA), block=(b,h) row -----------------------
// x written via LDS-transpose + coalesced dwordx4 copy (was 64 scalar f16
// global stores per thread -> vmem-issue bound).
__global__ __launch_bounds__(256) void k_gxdft(
      const float* __restrict__ gate, const float* __restrict__ inp,
      const float* __restrict__ enc_w, const float* __restrict__ enc_b,
      const f16_t* __restrict__ twA, f16_t* __restrict__ x,
      float2* __restrict__ fp0, float2* __restrict__ fp1){
  __shared__ __align__(16) char sm[41984];
  f16_t* Obt   = (f16_t*)sm;              // [64 c][274 w-pad]  35072 B
  float* gvs   = (float*)(sm + 35072);    // 256
  float4* ips  = (float4*)(sm + 36096);   // 256 float4
  float* ew    = (float*)(sm + 40448);    // 320
  float* eb    = (float*)(sm + 41728);    // 64
  int tid = threadIdx.x;
  int bh = blockIdx.x;                    // b*128 + h
  int b = bh >> 7, h = bh & 127;
  if (tid < 64) eb[tid] = enc_b[tid];
  for (int f = tid; f < 320; f += 256) ew[f] = enc_w[f];
  {                                        // gate load + input stage per pixel
    int px = tid;
    long hw = (long)h*256 + px;
    gvs[px] = gate[(long)b*32768 + hw];
    ips[px] = *(const float4*)(inp + ((long)b*32768 + hw)*4);
  }
  __syncthreads();
  int lane = tid & 63, wv = tid >> 6;
  {                                        // encoder: thread = (c, 64-px group)
    int c = lane, wg = wv;
    const float* wr2 = ew + c*5;
    float w0 = wr2[0], w1 = wr2[1], w2 = wr2[2], w3 = wr2[3], w4 = wr2[4];
    float ebc = eb[c];
    #pragma unroll 2
    for (int g8 = 0; g8 < 8; g8++){
      half8 hv;
      #pragma unroll
      for (int e2 = 0; e2 < 8; e2++){
        int i = g8*8 + e2;
        float4 ip = ips[wg*64 + i];
        float gv = gvs[wg*64 + i];
        float v = ebc + ip.x*w0 + ip.y*w1 + ip.z*w2 + ip.w*w3 + gv*w4;
        hv[e2] = (f16_t)v;
      }
      *(half8*)(Obt + c*274 + wg*64 + g8*8) = hv;
    }
  }
  __syncthreads();                         // Obt ready
  // coalesced transpose copy Obt -> x (8 dwordx4 stores/thread, dense 1KB/instr)
  {
    f16_t* xg = x + (long)bh*16384;
    for (int f = tid; f < 2048; f += 256){
      int px = f >> 3, c8 = f & 7;
      half8 hv;
      #pragma unroll
      for (int j = 0; j < 8; j++) hv[j] = Obt[(c8*8 + j)*274 + px];
      *(half8*)(xg + px*64 + c8*8) = hv;
    }
  }
  int n15 = lane & 15, quad = lane >> 4;
  int n = wv*16 + n15;
  #pragma unroll
  for (int half = 0; half < 2; half++){
    half8 bfr2[4];
    #pragma unroll
    for (int ks = 0; ks < 4; ks++)
      bfr2[ks] = *(const half8*)(Obt + n*274 + half*128 + ks*32 + quad*8);
    floatx4 dacc[2];
    dacc[0] = (floatx4){0.f,0.f,0.f,0.f};
    dacc[1] = (floatx4){0.f,0.f,0.f,0.f};
    #pragma unroll
    for (int hl = 0; hl < 2; hl++){
      #pragma unroll
      for (int mt = 0; mt < 2; mt++){
        #pragma unroll
        for (int ks = 0; ks < 4; ks++){
          half8 a = *(const half8*)(twA + half*8192 + hl*4096
                                    + (mt*16 + n15)*128 + ks*32 + quad*8);
          dacc[mt] = __builtin_amdgcn_mfma_f32_16x16x32_f16(a, bfr2[ks],
                                                            dacc[mt], 0,0,0);
        }
      }
    }
    float2* dst = half ? fp1 : fp0;
    #pragma unroll
    for (int mt = 0; mt < 2; mt++){
      int m0 = mt*16 + quad*4;
      if (m0 < 24){
        int ky0 = m0 >> 1;
        dst[(long)bh*768 + ky0*64 + n]     = make_float2(dacc[mt][0], dacc[mt][1]);
        dst[(long)bh*768 + (ky0+1)*64 + n] = make_float2(dacc[mt][2], dacc[mt][3]);
      }
    }
  }
}

// ---- FUSED spectral chain: dft_h + mode-mix + ifft_h, block=(b,ky) ---------
__global__ __launch_bounds__(256) void k_spec(const float2* __restrict__ s0,
      const float2* __restrict__ s1, int dual, const float2* __restrict__ thf_g,
      const float2* __restrict__ thi_g, const float2* __restrict__ wmix,
      int layer, float2* __restrict__ zi){
  __shared__ __align__(16) char sm[40960];
  float2* th  = (float2*)sm;            // 3072 f2: thf (A) then thi (C)
  float2* xch = (float2*)(sm + 24576);  // 2048 f2 staging (A)
  float2* mixL= (float2*)(sm + 24576);  // [24 j][64 o] (B->C), aliases xch
  int tid = threadIdx.x;
  int b = blockIdx.x / 12, ky = blockIdx.x % 12;
  int wv = tid >> 6, lane = tid & 63;
  for (int f = tid; f < 3072; f += 256) th[f] = thf_g[f];
  // Stage A: h-DFT. acc[q] = xft[j=q*4+wv][c=lane]
  float2 acc[6];
  #pragma unroll
  for (int q = 0; q < 6; q++) acc[q] = make_float2(0.f, 0.f);
  long base = (long)b*98304 + ky*64;
  for (int ch = 0; ch < 4; ch++){
    __syncthreads();
    for (int f = tid; f < 2048; f += 256){
      int hh = f >> 6, c = f & 63;
      long idx = base + (long)(ch*32 + hh)*768 + c;
      float2 v = s0[idx];
      if (dual){ float2 u = s1[idx]; v.x += u.x; v.y += u.y; }
      xch[f] = v;
    }
    __syncthreads();
    for (int hh = 0; hh < 32; hh++){
      float2 v = xch[hh*64 + lane];
      int hg = ch*32 + hh;
      #pragma unroll
      for (int q = 0; q < 6; q++){
        float2 t = th[hg*24 + q*4 + wv];
        acc[q].x += t.x*v.x - t.y*v.y;
        acc[q].y += t.x*v.y + t.y*v.x;
      }
    }
  }
  __syncthreads();                      // A done: xch & thf dead after here
  for (int f = tid; f < 3072; f += 256) th[f] = thi_g[f];   // stage thi
  // Stage B: mode-mix, register-resident via shfl
  float2 mout[6];
  #pragma unroll
  for (int q = 0; q < 6; q++){
    int j = q*4 + wv;
    const float2* wj = wmix + (((long)layer*288 + j*12 + ky))*4096;
    float re = 0.f, im = 0.f;
    #pragma unroll 8
    for (int i = 0; i < 64; i++){
      float vr = __shfl(acc[q].x, i);
      float vi = __shfl(acc[q].y, i);
      float2 ww = wj[i*64 + lane];
      re += vr*ww.x - vi*ww.y;
      im += vr*ww.y + vi*ww.x;
    }
    mout[q] = make_float2(re, im);
  }
  #pragma unroll
  for (int q = 0; q < 6; q++) mixL[(q*4 + wv)*64 + lane] = mout[q];
  __syncthreads();                      // mixL + thi ready
  // Stage C: inverse h-DFT
  float2 cr[24];
  #pragma unroll
  for (int j = 0; j < 24; j++) cr[j] = mixL[j*64 + lane];
  for (int qq = 0; qq < 32; qq++){
    int h = qq*4 + wv;
    float re = 0.f, im = 0.f;
    #pragma unroll
    for (int j = 0; j < 24; j++){
      float2 t = th[h*24 + j];
      re += t.x*cr[j].x - t.y*cr[j].y;
      im += t.x*cr[j].y + t.y*cr[j].x;
    }
    zi[((long)b*128 + h)*768 + ky*64 + lane] = make_float2(re, im);
  }
}

// ------- MFMA: inverse-w + skip + bias + (gelu), in place on x,
//         fused next-layer partial w-DFT via MFMA (twA hi/lo) ----------------
// Epilogue rewritten: acc -> T (LDS, stride-76 pad) scalar; then coalesced
// dwordx4 copy T->x (was 32 scalar f16 global stores/thread = vmem-issue
// bound). dodft B-fragments read directly from T (Obt eliminated).
__global__ __launch_bounds__(256) void k_iw_mfma(f16_t* __restrict__ x,
      const float2* __restrict__ zi, const float* __restrict__ ws_w,
      const float* __restrict__ ws_b, const f16_t* __restrict__ twzh,
      const f16_t* __restrict__ twA, float2* __restrict__ fp0,
      float2* __restrict__ fp1, int layer, int act, int dodft){
  __shared__ __align__(16) char sm[29696];
  f16_t* A1  = (f16_t*)sm;                  // [128 px][76] x in (phase1) / T out
  f16_t* Bzh = (f16_t*)(sm + 19456);        // [64 o][40]
  f16_t* Bzl = (f16_t*)(sm + 24576);        // [64 o][40]
  int tid = threadIdx.x;
  int blk = blockIdx.x;
  int half = blk & 1;
  long bh = blk >> 1;                       // b*128 + h
  int w0 = half*128;
  const f16_t* xrow = x + (bh*256 + w0)*64;
  for (int f = tid; f < 1024; f += 256){    // A1: 128 px x 8 chunks, 16B
    int px = f >> 3, c8 = f & 7;
    *(float4*)(A1 + px*76 + c8*8) = *(const float4*)(xrow + px*64 + c8*8);
  }
  const float2* zrow = zi + bh*768;
  for (int f = tid; f < 768; f += 256){     // z hi/lo split
    int o = f & 63, ky = f >> 6;
    float2 v = zrow[ky*64 + o];
    f16_t hr = (f16_t)v.x; f16_t hi_ = (f16_t)v.y;
    Bzh[o*40 + ky]      = hr;
    Bzh[o*40 + 12 + ky] = hi_;
    Bzl[o*40 + ky]      = (f16_t)(v.x - (float)hr);
    Bzl[o*40 + 12 + ky] = (f16_t)(v.y - (float)hi_);
  }
  if (tid < 64){                            // zero cols 24..31 (read by quad 3)
    float4 z4 = {0.f,0.f,0.f,0.f};
    *(float4*)(Bzh + tid*40 + 24) = z4;
    *(float4*)(Bzl + tid*40 + 24) = z4;
  }
  __syncthreads();
  int lane = tid & 63, wv = tid >> 6;
  int n15 = lane & 15, quad = lane >> 4;
  int n = wv*16 + n15;
  // B fragments: ws from global f32 (L2-hot, 16KB/layer), z from LDS
  half8 bws[2];
  {
    const float* wsl = ws_w + ((long)layer*64 + n)*64;
    #pragma unroll
    for (int kc = 0; kc < 2; kc++){
      float4 u0 = *(const float4*)(wsl + kc*32 + quad*8);
      float4 u1 = *(const float4*)(wsl + kc*32 + quad*8 + 4);
      half8 hb;
      hb[0]=(f16_t)u0.x; hb[1]=(f16_t)u0.y; hb[2]=(f16_t)u0.z; hb[3]=(f16_t)u0.w;
      hb[4]=(f16_t)u1.x; hb[5]=(f16_t)u1.y; hb[6]=(f16_t)u1.z; hb[7]=(f16_t)u1.w;
      bws[kc] = hb;
    }
  }
  float bias = ws_b[layer*64 + n];
  half8 bzh = *(const half8*)(Bzh + n*40 + quad*8);
  half8 bzl = *(const half8*)(Bzl + n*40 + quad*8);
  floatx4 acc[8];
  #pragma unroll
  for (int mt = 0; mt < 8; mt++){
    floatx4 c = {bias, bias, bias, bias};
    half8 ax0 = *(const half8*)(A1 + (mt*16 + n15)*76 + quad*8);
    half8 ax1 = *(const half8*)(A1 + (mt*16 + n15)*76 + 32 + quad*8);
    half8 atw = *(const half8*)(twzh + (w0 + mt*16 + n15)*32 + quad*8);
    c = __builtin_amdgcn_mfma_f32_16x16x32_f16(ax0, bws[0], c, 0,0,0);
    c = __builtin_amdgcn_mfma_f32_16x16x32_f16(ax1, bws[1], c, 0,0,0);
    c = __builtin_amdgcn_mfma_f32_16x16x32_f16(atw, bzh,    c, 0,0,0);
    c = __builtin_amdgcn_mfma_f32_16x16x32_f16(atw, bzl,    c, 0,0,0);
    acc[mt] = c;
  }
  __syncthreads();                           // all A1 reads done -> T reuse
  f16_t* T = A1;                             // [128 px][76]
  #pragma unroll
  for (int mt = 0; mt < 8; mt++){
    #pragma unroll
    for (int r = 0; r < 4; r++){
      float v = acc[mt][r];
      if (act) v = gelu_f(v);
      T[(mt*16 + quad*4 + r)*76 + n] = (f16_t)v;   // cheap scalar ds_write
    }
  }
  __syncthreads();                           // T complete
  {                                          // coalesced copy T -> x
    f16_t* xo = x + (bh*256 + w0)*64;
    for (int f = tid; f < 1024; f += 256){
      int px = f >> 3, c8 = f & 7;
      *(float4*)(xo + px*64 + c8*8) = *(const float4*)(T + px*76 + c8*8);
    }
  }
  if (dodft){                                // next-layer w-DFT; B-frags from T
    half8 bfr2[4];
    #pragma unroll
    for (int ks = 0; ks < 4; ks++){
      half8 hv;
      #pragma unroll
      for (int j = 0; j < 8; j++)
        hv[j] = T[(ks*32 + quad*8 + j)*76 + n];
      bfr2[ks] = hv;
    }
    floatx4 dacc[2];
    dacc[0] = (floatx4){0.f,0.f,0.f,0.f};
    dacc[1] = (floatx4){0.f,0.f,0.f,0.f};
    #pragma unroll
    for (int hl = 0; hl < 2; hl++){
      #pragma unroll
      for (int mt = 0; mt < 2; mt++){
        #pragma unroll
        for (int ks = 0; ks < 4; ks++){
          half8 a = *(const half8*)(twA + half*8192 + hl*4096
                                    + (mt*16 + n15)*128 + ks*32 + quad*8);
          dacc[mt] = __builtin_amdgcn_mfma_f32_16x16x32_f16(a, bfr2[ks],
                                                            dacc[mt], 0,0,0);
        }
      }
    }
    float2* dst = half ? fp1 : fp0;
    #pragma unroll
    for (int mt = 0; mt < 2; mt++){
      int m0 = mt*16 + quad*4;
      if (m0 < 24){
        int ky0 = m0 >> 1;
        dst[bh*768 + ky0*64 + n]     = make_float2(dacc[mt][0], dacc[mt][1]);
        dst[bh*768 + (ky0+1)*64 + n] = make_float2(dacc[mt][2], dacc[mt][3]);
      }
    }
  }
}

// ------- MFMA conv 3x3 (per-batch weights) + gelu + head, fused; 64-px tiles -
__global__ __launch_bounds__(256) void k_conv_head(const f16_t* __restrict__ x,
      const float* __restrict__ ext, const f16_t* __restrict__ wT,
      const float* __restrict__ tb, const f16_t* __restrict__ f1T,
      const float* __restrict__ f1_b, const f16_t* __restrict__ f2T,
      const float* __restrict__ f2_b, const f16_t* __restrict__ f3T,
      const float* __restrict__ f3_b, float* __restrict__ out){
  __shared__ __align__(16) char sm[29824];
  f16_t* hf   = (f16_t*)sm;                 // [64][72]   (phase: hf -> z1 read)
  f16_t* z1   = (f16_t*)(sm + 9216);        // [64][136]
  f16_t* z2   = (f16_t*)sm;                 // [64][72]   aliases hf (hf dead)
  float* tbs  = (float*)(sm + 28512);       // above xt halo region
  float* f1bs = (float*)(sm + 28768);
  float* f2bs = (float*)(sm + 29280);
  f16_t* f3s  = (f16_t*)(sm + 29536);
  float* f3bs = (float*)(sm + 29792);
  f16_t* xt   = (f16_t*)sm;                 // [3][66][72] (conv phase) 28512 B

  int tid = threadIdx.x;
  int blk = blockIdx.x;
  int wc = blk & 3, h = (blk >> 2) & 127, b = blk >> 9;
  int w0 = wc*64;
  int t_idx = (int)ext[b*6+3] - 5;

  if (tid < 64) tbs[tid] = tb[t_idx*64 + tid];
  else if (tid < 192) f1bs[tid-64] = f1_b[tid-64];
  else f2bs[tid-192] = f2_b[tid-192];
  if (tid < 128) f3s[tid] = f3T[tid];
  if (tid < 2) f3bs[tid] = f3_b[tid];

  // main interior 64 px: pow2 indexing, only h-bounds check
  for (int f = tid; f < 1536; f += 256){
    int c8 = f & 7, px = (f >> 3) & 63, dy = f >> 9;
    int hh = h - 1 + dy;
    float4 v = {0.f,0.f,0.f,0.f};
    if (hh >= 0 && hh < HH_)
      v = *(const float4*)(x + (((long)b*HH_ + hh)*WW_ + w0 + px)*64 + c8*8);
    *(float4*)(xt + (dy*66 + px + 1)*72 + c8*8) = v;
  }
  if (tid < 48){                            // halo columns pxl = 0 and 65
    int c8 = tid & 7, r = tid >> 3;         // r: 0..5
    int dy = r >> 1, side = r & 1;
    int pxl = side ? 65 : 0;
    int hh = h - 1 + dy, wg = w0 - 1 + pxl;
    float4 v = {0.f,0.f,0.f,0.f};
    if (hh >= 0 && hh < HH_ && wg >= 0 && wg < WW_)
      v = *(const float4*)(x + (((long)b*HH_ + hh)*WW_ + wg)*64 + c8*8);
    *(float4*)(xt + (dy*66 + pxl)*72 + c8*8) = v;
  }
  __syncthreads();

  int lane = tid & 63, wv = tid >> 6;
  int n15 = lane & 15, quad = lane >> 4;
  int n = wv*16 + n15;

  floatx4 acc[4];
  {
    float bias0 = tbs[n];                   // per-thread const -> acc init
    #pragma unroll
    for (int mt = 0; mt < 4; mt++) acc[mt] = (floatx4){bias0,bias0,bias0,bias0};
  }
  const f16_t* wTt = wT + (long)t_idx*36864;
  for (int tap = 0; tap < 9; tap++){
    int dy = tap/3, dx = tap%3;
    const f16_t* wrow = wTt + (tap*64 + wv*16 + n15)*64;
    #pragma unroll
    for (int kc = 0; kc < 2; kc++){
      half8 bfrag = *(const half8*)(wrow + kc*32 + quad*8);
      #pragma unroll
      for (int mt = 0; mt < 4; mt++){
        int p = mt*16 + n15 + dx;
        half8 a = *(const half8*)(xt + (dy*66 + p)*72 + kc*32 + quad*8);
        acc[mt] = __builtin_amdgcn_mfma_f32_16x16x32_f16(a, bfrag, acc[mt], 0,0,0);
      }
    }
  }
  __syncthreads();                           // xt dead
  {
    #pragma unroll
    for (int mt = 0; mt < 4; mt++){
      #pragma unroll
      for (int r = 0; r < 4; r++){
        int m = mt*16 + quad*4 + r;
        hf[m*72 + n] = (f16_t)gelu_f(acc[mt][r]);
      }
    }
  }
  __syncthreads();
  // z1 = gelu(hf . f1^T + f1_b): M=64 N=128 K=64
  #pragma unroll
  for (int nt = 0; nt < 2; nt++){
    int n1 = wv*32 + nt*16 + n15;
    float bias = f1bs[n1];
    half8 bf0 = *(const half8*)(f1T + n1*64 + quad*8);
    half8 bf1 = *(const half8*)(f1T + n1*64 + 32 + quad*8);
    #pragma unroll
    for (int mt = 0; mt < 4; mt++){
      floatx4 c = {bias, bias, bias, bias};
      half8 a0 = *(const half8*)(hf + (mt*16 + n15)*72 + quad*8);
      half8 a1 = *(const half8*)(hf + (mt*16 + n15)*72 + 32 + quad*8);
      c = __builtin_amdgcn_mfma_f32_16x16x32_f16(a0, bf0, c, 0,0,0);
      c = __builtin_amdgcn_mfma_f32_16x16x32_f16(a1, bf1, c, 0,0,0);
      #pragma unroll
      for (int r = 0; r < 4; r++){
        int m = mt*16 + quad*4 + r;
        z1[m*136 + n1] = (f16_t)gelu_f(c[r]);
      }
    }
  }
  __syncthreads();
  // z2 = gelu(z1 . f2^T + f2_b): M=64 N=64 K=128  (z2 overwrites dead hf)
  {
    float bias = f2bs[n];
    half8 bf[4];
    #pragma unroll
    for (int kc = 0; kc < 4; kc++)
      bf[kc] = *(const half8*)(f2T + n*128 + kc*32 + quad*8);
    #pragma unroll
    for (int mt = 0; mt < 4; mt++){
      floatx4 c = {bias, bias, bias, bias};
      #pragma unroll
      for (int kc = 0; kc < 4; kc++){
        half8 a = *(const half8*)(z1 + (mt*16 + n15)*136 + kc*32 + quad*8);
        c = __builtin_amdgcn_mfma_f32_16x16x32_f16(a, bf[kc], c, 0,0,0);
      }
      #pragma unroll
      for (int r = 0; r < 4; r++){
        int m = mt*16 + quad*4 + r;
        z2[m*72 + n] = (f16_t)gelu_f(c[r]);
      }
    }
  }
  __syncthreads();
  // f3: out[px][0..1]
  if (tid < 128){
    int px = tid >> 1, oo = tid & 1;
    const f16_t* zr = z2 + px*72;
    const f16_t* fr = f3s + oo*64;
    float a = f3bs[oo];
    #pragma unroll
    for (int g = 0; g < 8; g++){
      half8 zv = *(const half8*)(zr + g*8);
      half8 wv2 = *(const half8*)(fr + g*8);
#if __has_builtin(__builtin_amdgcn_fdot2)
      #pragma unroll
      for (int q = 0; q < 4; q++){
        half2v za = {zv[2*q], zv[2*q+1]};
        half2v wa = {wv2[2*q], wv2[2*q+1]};
        a = __builtin_amdgcn_fdot2(za, wa, a, false);
      }
#else
      #pragma unroll
      for (int q = 0; q < 8; q++) a += (float)zv[q]*(float)wv2[q];
#endif
    }
    out[(((long)b*HH_ + h)*WW_ + w0 + px)*2 + oo] = a;
  }
}

extern "C" void kernel_launch(void* const* d_in, const int* in_sizes, int n_in,
                              void* d_out, int out_size, void* d_ws, size_t ws_size,
                              hipStream_t stream){
  const float* inp     = (const float*)d_in[0];
  const float* ext     = (const float*)d_in[1];
  const float* enc_w   = (const float*)d_in[2];
  const float* enc_b   = (const float*)d_in[3];
  const float* w1r     = (const float*)d_in[4];
  const float* w1i     = (const float*)d_in[5];
  const float* w2r     = (const float*)d_in[6];
  const float* w2i     = (const float*)d_in[7];
  const float* ws_w    = (const float*)d_in[8];
  const float* ws_b    = (const float*)d_in[9];
  const float* day_emb = (const float*)d_in[10];
  const float* hour_emb= (const float*)d_in[11];
  const float* e1_w    = (const float*)d_in[12];
  const float* e1_b    = (const float*)d_in[13];
  const float* e2_w    = (const float*)d_in[14];
  const float* e2_b    = (const float*)d_in[15];
  const float* tw      = (const float*)d_in[16];
  const float* tb      = (const float*)d_in[17];
  const float* f1_w    = (const float*)d_in[18];
  const float* f1_b    = (const float*)d_in[19];
  const float* f2_w    = (const float*)d_in[20];
  const float* f2_b    = (const float*)d_in[21];
  const float* f3_w    = (const float*)d_in[22];
  const float* f3_b    = (const float*)d_in[23];
  float* outp = (float*)d_out;

  const size_t need = 248652032;
  if (ws_size < need){
    k_diag<<<dim3(1), dim3(64), 0, stream>>>(outp, (float)(ws_size >> 20));
    return;
  }
  char* p = (char*)d_ws;
  f16_t*  x    = (f16_t*)(p);                    // 134217728 B
  float2* fp0  = (float2*)(p + 134217728);       // 25165824 B
  float2* fp1  = (float2*)(p + 159383552);       // 25165824 B
  float2* zi   = (float2*)(p + 184549376);       // 25165824 B
  float*  gate = (float*)(p + 184549376);        // 4 MB, aliases zi (dead till spec)
  float*  gg   = (float*)(p + 209715200);        // 8 KB, in old twf region
  float2* thf  = (float2*)(p + 209739776);       // 24576 B
  float2* thi  = (float2*)(p + 209764352);       // 24576 B
  f16_t*  twzh = (f16_t*)(p + 209788928);        // 16384 B
  f16_t*  wT   = (f16_t*)(p + 209805312);        // 1032192 B
  f16_t*  f1T  = (f16_t*)(p + 210837504);        // 16384 B
  f16_t*  f2T  = (f16_t*)(p + 210853888);        // 16384 B
  f16_t*  f3T  = (f16_t*)(p + 210870272);        // 256 B
  float2* wmix = (float2*)(p + 210870528);       // 37748736 B
  f16_t*  twA  = (f16_t*)(p + 248619264);        // 32768 B

  k_prep<<<dim3(1009), dim3(256), 0, stream>>>(gg, thf, thi, twzh,
      f1_w, f2_w, f3_w, f1T, f2T, f3T, tw, wT, w1r, w1i, w2r, w2i, wmix, twA,
      ext, day_emb, hour_emb, e1_w, e1_b);
  k_gate<<<dim3(128), dim3(256), 0, stream>>>(gg, e2_w, e2_b, gate);
  k_gxdft<<<dim3(4096), dim3(256), 0, stream>>>(gate, inp, enc_w, enc_b,
                                                twA, x, fp0, fp1);
  for (int l = 0; l < 4; l++){
    k_spec<<<dim3(384), dim3(256), 0, stream>>>(fp0, fp1, 1,
                                                thf, thi, wmix, l, zi);
    k_iw_mfma<<<dim3(8192), dim3(256), 0, stream>>>(x, zi, ws_w, ws_b, twzh,
                       twA, fp0, fp1, l, (l < 3) ? 1 : 0, (l < 3) ? 1 : 0);
  }
  k_conv_head<<<dim3(16384), dim3(256), 0, stream>>>(x, ext, wT, tb,
                     f1T, f1_b, f2T, f2_b, f3T, f3_b, outp);
}

// Round 9
// 1198.679 us; speedup vs baseline: 1.0943x; 1.0943x over previous
//
#include <hip/hip_runtime.h>
#include <math.h>

#define BB 32
#define HH_ 128
#define WW_ 256

typedef _Float16 f16_t;
typedef _Float16 half8 __attribute__((ext_vector_type(8)));
typedef _Float16 half4 __attribute__((ext_vector_type(4)));
typedef _Float16 half2v __attribute__((ext_vector_type(2)));
typedef float floatx4 __attribute__((ext_vector_type(4)));

// Branch-free fast gelu, relu-form (A-S 7.1.26, |erf err| <= 1.5e-7).
__device__ __forceinline__ float gelu_f(float v){
  float av = __builtin_fabsf(v);
  float s = av * 0.70710678118654752f;
  float k = __builtin_amdgcn_rcpf(__builtin_fmaf(0.3275911f, s, 1.0f));
  float p = __builtin_fmaf(1.061405429f, k, -1.453152027f);
  p = __builtin_fmaf(p, k, 1.421413741f);
  p = __builtin_fmaf(p, k, -0.284496736f);
  p = __builtin_fmaf(p, k, 0.254829592f);
  p = p * k;
  float e = __expf(-s * s);
  float q = 0.5f * av * p;
  return __builtin_fmaf(-q, e, fmaxf(v, 0.f));
}

// Exact-reduced DFT twiddle: angle = sgn * 2*pi * (prod mod N) / N.
__device__ __forceinline__ float2 twiddle(int prod, int N, float sgn){
  int m = prod & (N - 1);
  float a = sgn * (6.2831853071795864769f / (float)N) * (float)m;
  return make_float2(cosf(a), sinf(a));
}

__global__ void k_diag(float* out, float v){ out[threadIdx.x] = v; }

// ---- merged prep: [0,113) tables+head-f16; [113,169) wprep;
//      [169,937) mixprep; [937,1001) twA; [1001,1009) ext-MLP g vector -------
__global__ __launch_bounds__(256) void k_prep(
      float* gg, float2* thf, float2* thi, f16_t* twzh,
      const float* __restrict__ f1_w, const float* __restrict__ f2_w,
      const float* __restrict__ f3_w, f16_t* f1T, f16_t* f2T, f16_t* f3T,
      const float* __restrict__ tw, f16_t* __restrict__ wT,
      const float* __restrict__ w1r, const float* __restrict__ w1i,
      const float* __restrict__ w2r, const float* __restrict__ w2i,
      float2* __restrict__ wmix, f16_t* __restrict__ twA,
      const float* __restrict__ ext, const float* __restrict__ day_emb,
      const float* __restrict__ hour_emb, const float* __restrict__ e1_w,
      const float* __restrict__ e1_b){
  __shared__ __align__(16) char smp[53248];
  int blk = blockIdx.x, tid = threadIdx.x;
  if (blk < 113){
    int t = blk*256 + tid;
    if (t < 3072){
      // spare slot
    } else if (t < 6144){                // forward h-DFT: [h][j]
      int f = t-3072; int h = f/24, j = f%24;
      int kx = (j<12)? j : j+104;
      thf[f] = twiddle(h*kx, 128, -1.f);
    } else if (t < 9216){                // inverse h (includes 1/128)
      int f = t-6144; int h = f/24, j = f%24;
      int kx = (j<12)? j : j+104;
      float2 c = twiddle(h*kx, 128, 1.f);
      thi[f] = make_float2(c.x*0.0078125f, c.y*0.0078125f);
    } else if (t < 12288){               // inverse w (c2r) coefs, f16
      int f = t-9216; int w = f/12, ky = f%12;
      float2 c = twiddle(w*ky, 256, 1.f);
      float s = (ky==0)? 0.00390625f : 0.0078125f;   // (1 or 2)/256
      twzh[w*32 + ky]      = (f16_t)( s*c.x);
      twzh[w*32 + 12 + ky] = (f16_t)(-s*c.y);
      if (ky < 8) twzh[w*32 + 24 + ky] = (f16_t)0.f;
    } else {
      int t2 = t - 12288;                // head weights -> f16
      if (t2 < 8192) f1T[t2] = (f16_t)f1_w[t2];
      else if (t2 < 16384) f2T[t2-8192] = (f16_t)f2_w[t2-8192];
      else if (t2 < 16512) f3T[t2-16384] = (f16_t)f3_w[t2-16384];
    }
  } else if (blk < 169){                 // conv weight transpose via LDS
    float* s = (float*)smp;              // [o16][c][tap]
    int b2 = blk - 113;
    int og = b2 & 3, tt = b2 >> 2;
    const float* src = tw + (long)tt*36864 + og*9216;
    for (int f = tid; f < 9216; f += 256) s[f] = src[f];
    __syncthreads();
    for (int f = tid; f < 9216; f += 256){
      int c = f & 63; int r = f >> 6;
      int o16 = r % 16, tap = r / 16;
      float v = s[(o16*64 + c)*9 + tap];
      wT[(((long)tt*9 + tap)*64 + og*16 + o16)*64 + c] = (f16_t)v;
    }
  } else if (blk < 937){                 // spectral weight transpose via LDS
    float* sr = (float*)smp;             // 6656 f
    float* si = (float*)(smp + 26624);   // 6656 f
    int b2 = blk - 169;                  // < 768
    int ig  = b2 & 7;
    int kx  = (b2 >> 3) % 12;
    int sel = (b2 / 96) & 1;
    int l   = b2 / 192;
    const float* wr = sel ? w2r : w1r;
    const float* wi = sel ? w2i : w1i;
    for (int f = tid; f < 6144; f += 256){
      int i8 = f / 768; int rem = f % 768;
      int o = rem / 12, ky = rem % 12;
      long addr = (((long)l*64 + ig*8 + i8)*64 + o)*144 + kx*12 + ky;
      sr[(i8*64 + o)*13 + ky] = wr[addr];
      si[(i8*64 + o)*13 + ky] = wi[addr];
    }
    __syncthreads();
    int j = sel ? (kx + 12) : kx;
    for (int f = tid; f < 6144; f += 256){
      int o = f & 63; int r = f >> 6;
      int ky = r % 12, i8 = r / 12;
      int sidx = (i8*64 + o)*13 + ky;
      wmix[(((long)l*288 + j*12 + ky))*4096 + (ig*8 + i8)*64 + o] =
          make_float2(sr[sidx], si[sidx]);
    }
  } else if (blk < 1001){                // twA[half][hl][32 m][128 k] f16
    int t = (blk - 937)*256 + tid;       // < 16384
    int halfi = t >> 13, r = t & 8191;
    int hl = r >> 12, r2 = r & 4095;
    int m = r2 >> 7, k = r2 & 127;
    f16_t v = (f16_t)0.f;
    if (m < 24){
      int ky = m >> 1, ri = m & 1;
      int w = halfi*128 + k;
      float2 c = twiddle(w*ky, 256, -1.f);
      float t32 = ri ? c.y : c.x;
      f16_t hi = (f16_t)t32;
      v = hl ? (f16_t)(t32 - (float)hi) : hi;
    }
    twA[t] = v;
  } else {                               // ext MLP g: gg[32 b][64 j]
    int b2 = blk - 1001;                 // 0..7
    int bloc = tid >> 6, j = tid & 63;
    int b = b2*4 + bloc;
    const float* e = ext + b*6;
    float emb[6];
    emb[0] = e[0];
    int d  = (int)e[2];
    emb[1] = day_emb[d*2];  emb[2] = day_emb[d*2+1];
    int hr = (int)e[3];
    emb[3] = hour_emb[hr*3]; emb[4] = hour_emb[hr*3+1]; emb[5] = hour_emb[hr*3+2];
    float acc = e1_b[j];
    #pragma unroll
    for (int k = 0; k < 6; k++) acc += emb[k]*e1_w[j*6+k];
    gg[b*64 + j] = gelu_f(acc);
  }
}

// ---- gate precompute: gate[b][hw] = gelu(g[b] . e2_w[hw] + e2_b[hw]) --------
__global__ __launch_bounds__(256) void k_gate(const float* __restrict__ gg,
      const float* __restrict__ e2_w, const float* __restrict__ e2_b,
      float* __restrict__ gate){
  __shared__ float gs[2048];
  int tid = threadIdx.x;
  for (int f = tid; f < 2048; f += 256) gs[f] = gg[f];
  __syncthreads();
  long hw = (long)blockIdx.x*256 + tid;
  const float4* wrow = (const float4*)(e2_w + hw*64);
  float4 w[16];
  #pragma unroll
  for (int k = 0; k < 16; k++) w[k] = wrow[k];
  float eb2 = e2_b[hw];
  for (int b = 0; b < 32; b++){
    const float* g = gs + b*64;
    float acc = eb2;
    #pragma unroll
    for (int k = 0; k < 16; k++){
      float4 v = w[k];
      acc += v.x*g[4*k] + v.y*g[4*k+1] + v.z*g[4*k+2] + v.w*g[4*k+3];
    }
    gate[(long)b*32768 + hw] = gelu_f(acc);
  }
}

// ---- encoder + layer-0 w-DFT (MFMA), block=(b,h) row; gate precomputed -----
__global__ __launch_bounds__(256) void k_gxdft(
      const float* __restrict__ gate, const float* __restrict__ inp,
      const float* __restrict__ enc_w, const float* __restrict__ enc_b,
      const f16_t* __restrict__ twA, f16_t* __restrict__ x,
      float2* __restrict__ fp0, float2* __restrict__ fp1){
  __shared__ __align__(16) char sm[41984];
  f16_t* Obt   = (f16_t*)sm;              // [64 c][274 w-pad]  35072 B
  float* gvs   = (float*)(sm + 35072);    // 256
  float4* ips  = (float4*)(sm + 36096);   // 256 float4
  float* ew    = (float*)(sm + 40448);    // 320
  float* eb    = (float*)(sm + 41728);    // 64
  int tid = threadIdx.x;
  int bh = blockIdx.x;                    // b*128 + h
  int b = bh >> 7, h = bh & 127;
  if (tid < 64) eb[tid] = enc_b[tid];
  for (int f = tid; f < 320; f += 256) ew[f] = enc_w[f];
  {                                        // gate load + input stage per pixel
    int px = tid;
    long hw = (long)h*256 + px;
    gvs[px] = gate[(long)b*32768 + hw];
    ips[px] = *(const float4*)(inp + ((long)b*32768 + hw)*4);
  }
  __syncthreads();
  int lane = tid & 63, wv = tid >> 6;
  {                                        // encoder: thread = (c, 64-px group)
    int c = lane, wg = wv;
    const float* wr2 = ew + c*5;
    float w0 = wr2[0], w1 = wr2[1], w2 = wr2[2], w3 = wr2[3], w4 = wr2[4];
    float ebc = eb[c];
    f16_t* xo = x + ((long)bh*256 + wg*64)*64 + c;
    #pragma unroll 2
    for (int g8 = 0; g8 < 8; g8++){
      half8 hv;
      #pragma unroll
      for (int e2 = 0; e2 < 8; e2++){
        int i = g8*8 + e2;
        float4 ip = ips[wg*64 + i];
        float gv = gvs[wg*64 + i];
        float v = ebc + ip.x*w0 + ip.y*w1 + ip.z*w2 + ip.w*w3 + gv*w4;
        f16_t hval = (f16_t)v;
        hv[e2] = hval;
        xo[i*64] = hval;                   // coalesced across lanes (same i)
      }
      *(half8*)(Obt + c*274 + wg*64 + g8*8) = hv;
    }
  }
  __syncthreads();                         // Obt ready
  int n15 = lane & 15, quad = lane >> 4;
  int n = wv*16 + n15;
  #pragma unroll
  for (int half = 0; half < 2; half++){
    half8 bfr2[4];
    #pragma unroll
    for (int ks = 0; ks < 4; ks++)
      bfr2[ks] = *(const half8*)(Obt + n*274 + half*128 + ks*32 + quad*8);
    floatx4 dacc[2];
    dacc[0] = (floatx4){0.f,0.f,0.f,0.f};
    dacc[1] = (floatx4){0.f,0.f,0.f,0.f};
    #pragma unroll
    for (int hl = 0; hl < 2; hl++){
      #pragma unroll
      for (int mt = 0; mt < 2; mt++){
        #pragma unroll
        for (int ks = 0; ks < 4; ks++){
          half8 a = *(const half8*)(twA + half*8192 + hl*4096
                                    + (mt*16 + n15)*128 + ks*32 + quad*8);
          dacc[mt] = __builtin_amdgcn_mfma_f32_16x16x32_f16(a, bfr2[ks],
                                                            dacc[mt], 0,0,0);
        }
      }
    }
    float2* dst = half ? fp1 : fp0;
    #pragma unroll
    for (int mt = 0; mt < 2; mt++){
      int m0 = mt*16 + quad*4;
      if (m0 < 24){
        int ky0 = m0 >> 1;
        dst[(long)bh*768 + ky0*64 + n]     = make_float2(dacc[mt][0], dacc[mt][1]);
        dst[(long)bh*768 + (ky0+1)*64 + n] = make_float2(dacc[mt][2], dacc[mt][3]);
      }
    }
  }
}

// ---- FUSED spectral chain: dft_h + mode-mix + ifft_h, block=(b,ky) ---------
__global__ __launch_bounds__(256) void k_spec(const float2* __restrict__ s0,
      const float2* __restrict__ s1, int dual, const float2* __restrict__ thf_g,
      const float2* __restrict__ thi_g, const float2* __restrict__ wmix,
      int layer, float2* __restrict__ zi){
  __shared__ __align__(16) char sm[40960];
  float2* th  = (float2*)sm;            // 3072 f2: thf (A) then thi (C)
  float2* xch = (float2*)(sm + 24576);  // 2048 f2 staging (A)
  float2* mixL= (float2*)(sm + 24576);  // [24 j][64 o] (B->C), aliases xch
  int tid = threadIdx.x;
  int b = blockIdx.x / 12, ky = blockIdx.x % 12;
  int wv = tid >> 6, lane = tid & 63;
  for (int f = tid; f < 3072; f += 256) th[f] = thf_g[f];
  // Stage A: h-DFT. acc[q] = xft[j=q*4+wv][c=lane]
  float2 acc[6];
  #pragma unroll
  for (int q = 0; q < 6; q++) acc[q] = make_float2(0.f, 0.f);
  long base = (long)b*98304 + ky*64;
  for (int ch = 0; ch < 4; ch++){
    __syncthreads();
    for (int f = tid; f < 2048; f += 256){
      int hh = f >> 6, c = f & 63;
      long idx = base + (long)(ch*32 + hh)*768 + c;
      float2 v = s0[idx];
      if (dual){ float2 u = s1[idx]; v.x += u.x; v.y += u.y; }
      xch[f] = v;
    }
    __syncthreads();
    for (int hh = 0; hh < 32; hh++){
      float2 v = xch[hh*64 + lane];
      int hg = ch*32 + hh;
      #pragma unroll
      for (int q = 0; q < 6; q++){
        float2 t = th[hg*24 + q*4 + wv];
        acc[q].x += t.x*v.x - t.y*v.y;
        acc[q].y += t.x*v.y + t.y*v.x;
      }
    }
  }
  __syncthreads();                      // A done: xch & thf dead after here
  for (int f = tid; f < 3072; f += 256) th[f] = thi_g[f];   // stage thi
  // Stage B: mode-mix, register-resident via shfl
  float2 mout[6];
  #pragma unroll
  for (int q = 0; q < 6; q++){
    int j = q*4 + wv;
    const float2* wj = wmix + (((long)layer*288 + j*12 + ky))*4096;
    float re = 0.f, im = 0.f;
    #pragma unroll 8
    for (int i = 0; i < 64; i++){
      float vr = __shfl(acc[q].x, i);
      float vi = __shfl(acc[q].y, i);
      float2 ww = wj[i*64 + lane];
      re += vr*ww.x - vi*ww.y;
      im += vr*ww.y + vi*ww.x;
    }
    mout[q] = make_float2(re, im);
  }
  #pragma unroll
  for (int q = 0; q < 6; q++) mixL[(q*4 + wv)*64 + lane] = mout[q];
  __syncthreads();                      // mixL + thi ready
  // Stage C: inverse h-DFT
  float2 cr[24];
  #pragma unroll
  for (int j = 0; j < 24; j++) cr[j] = mixL[j*64 + lane];
  for (int qq = 0; qq < 32; qq++){
    int h = qq*4 + wv;
    float re = 0.f, im = 0.f;
    #pragma unroll
    for (int j = 0; j < 24; j++){
      float2 t = th[h*24 + j];
      re += t.x*cr[j].x - t.y*cr[j].y;
      im += t.x*cr[j].y + t.y*cr[j].x;
    }
    zi[((long)b*128 + h)*768 + ky*64 + lane] = make_float2(re, im);
  }
}

// ------- MFMA: inverse-w + skip + bias + (gelu), in place on x,
//         fused next-layer partial w-DFT via MFMA (twA hi/lo) ----------------
__global__ __launch_bounds__(256) void k_iw_mfma(f16_t* __restrict__ x,
      const float2* __restrict__ zi, const float* __restrict__ ws_w,
      const float* __restrict__ ws_b, const f16_t* __restrict__ twzh,
      const f16_t* __restrict__ twA, float2* __restrict__ fp0,
      float2* __restrict__ fp1, int layer, int act, int dodft){
  __shared__ __align__(16) char sm[28672];
  f16_t* A1  = (f16_t*)sm;                  // [128 px][72] x channels (phase1)
  f16_t* Bzh = (f16_t*)(sm + 18432);        // [64 o][40]: hr(0-11) hi(12-23) 0(24-31)
  f16_t* Bzl = (f16_t*)(sm + 23552);        // [64 o][40]: lo_r lo_i 0
  f16_t* Obt = (f16_t*)sm;                  // [64 c][136] phase2 (dodft), alias A1
  int tid = threadIdx.x;
  int blk = blockIdx.x;
  int half = blk & 1;
  long bh = blk >> 1;                       // b*128 + h
  int w0 = half*128;
  const f16_t* xrow = x + (bh*256 + w0)*64;
  for (int f = tid; f < 1024; f += 256){    // A1: 128 px x 8 chunks, 16B
    int px = f >> 3, c8 = f & 7;
    *(float4*)(A1 + px*72 + c8*8) = *(const float4*)(xrow + px*64 + c8*8);
  }
  const float2* zrow = zi + bh*768;
  for (int f = tid; f < 768; f += 256){     // z hi/lo split
    int o = f & 63, ky = f >> 6;
    float2 v = zrow[ky*64 + o];
    f16_t hr = (f16_t)v.x; f16_t hi_ = (f16_t)v.y;
    Bzh[o*40 + ky]      = hr;
    Bzh[o*40 + 12 + ky] = hi_;
    Bzl[o*40 + ky]      = (f16_t)(v.x - (float)hr);
    Bzl[o*40 + 12 + ky] = (f16_t)(v.y - (float)hi_);
  }
  if (tid < 64){                            // zero cols 24..31 (read by quad 3)
    float4 z4 = {0.f,0.f,0.f,0.f};
    *(float4*)(Bzh + tid*40 + 24) = z4;
    *(float4*)(Bzl + tid*40 + 24) = z4;
  }
  __syncthreads();
  int lane = tid & 63, wv = tid >> 6;
  int n15 = lane & 15, quad = lane >> 4;
  int n = wv*16 + n15;
  // B fragments: ws from global f32 (L2-hot, 16KB/layer), z from LDS
  half8 bws[2];
  {
    const float* wsl = ws_w + ((long)layer*64 + n)*64;
    #pragma unroll
    for (int kc = 0; kc < 2; kc++){
      float4 u0 = *(const float4*)(wsl + kc*32 + quad*8);
      float4 u1 = *(const float4*)(wsl + kc*32 + quad*8 + 4);
      half8 hb;
      hb[0]=(f16_t)u0.x; hb[1]=(f16_t)u0.y; hb[2]=(f16_t)u0.z; hb[3]=(f16_t)u0.w;
      hb[4]=(f16_t)u1.x; hb[5]=(f16_t)u1.y; hb[6]=(f16_t)u1.z; hb[7]=(f16_t)u1.w;
      bws[kc] = hb;
    }
  }
  float bias = ws_b[layer*64 + n];
  half8 bzh = *(const half8*)(Bzh + n*40 + quad*8);
  half8 bzl = *(const half8*)(Bzl + n*40 + quad*8);
  floatx4 acc[8];
  #pragma unroll
  for (int mt = 0; mt < 8; mt++){
    floatx4 c = {bias, bias, bias, bias};   // bias folded into accumulator
    half8 ax0 = *(const half8*)(A1 + (mt*16 + n15)*72 + quad*8);
    half8 ax1 = *(const half8*)(A1 + (mt*16 + n15)*72 + 32 + quad*8);
    half8 atw = *(const half8*)(twzh + (w0 + mt*16 + n15)*32 + quad*8);
    c = __builtin_amdgcn_mfma_f32_16x16x32_f16(ax0, bws[0], c, 0,0,0);
    c = __builtin_amdgcn_mfma_f32_16x16x32_f16(ax1, bws[1], c, 0,0,0);
    c = __builtin_amdgcn_mfma_f32_16x16x32_f16(atw, bzh,    c, 0,0,0);
    c = __builtin_amdgcn_mfma_f32_16x16x32_f16(atw, bzl,    c, 0,0,0);
    acc[mt] = c;
  }
  __syncthreads();                           // A1/Bz dead -> Obt
  f16_t* xo = x + (bh*256 + w0)*64;
  #pragma unroll
  for (int mt = 0; mt < 8; mt++){
    half4 hv;
    #pragma unroll
    for (int r = 0; r < 4; r++){
      float v = acc[mt][r];
      if (act) v = gelu_f(v);
      hv[r] = (f16_t)v;
      xo[(mt*16 + quad*4 + r)*64 + n] = hv[r];
    }
    if (dodft) *(half4*)(Obt + n*136 + mt*16 + quad*4) = hv;
  }
  if (dodft){                                // next-layer w-DFT; twA from global
    __syncthreads();
    half8 bfr2[4];
    #pragma unroll
    for (int ks = 0; ks < 4; ks++)
      bfr2[ks] = *(const half8*)(Obt + n*136 + ks*32 + quad*8);
    floatx4 dacc[2];
    dacc[0] = (floatx4){0.f,0.f,0.f,0.f};
    dacc[1] = (floatx4){0.f,0.f,0.f,0.f};
    #pragma unroll
    for (int hl = 0; hl < 2; hl++){
      #pragma unroll
      for (int mt = 0; mt < 2; mt++){
        #pragma unroll
        for (int ks = 0; ks < 4; ks++){
          half8 a = *(const half8*)(twA + half*8192 + hl*4096
                                    + (mt*16 + n15)*128 + ks*32 + quad*8);
          dacc[mt] = __builtin_amdgcn_mfma_f32_16x16x32_f16(a, bfr2[ks],
                                                            dacc[mt], 0,0,0);
        }
      }
    }
    float2* dst = half ? fp1 : fp0;
    #pragma unroll
    for (int mt = 0; mt < 2; mt++){
      int m0 = mt*16 + quad*4;
      if (m0 < 24){
        int ky0 = m0 >> 1;
        dst[bh*768 + ky0*64 + n]     = make_float2(dacc[mt][0], dacc[mt][1]);
        dst[bh*768 + (ky0+1)*64 + n] = make_float2(dacc[mt][2], dacc[mt][3]);
      }
    }
  }
}

// ------- MFMA conv 3x3 (per-batch weights) + gelu + head, fused; 64-px tiles -
__global__ __launch_bounds__(256) void k_conv_head(const f16_t* __restrict__ x,
      const float* __restrict__ ext, const f16_t* __restrict__ wT,
      const float* __restrict__ tb, const f16_t* __restrict__ f1T,
      const float* __restrict__ f1_b, const f16_t* __restrict__ f2T,
      const float* __restrict__ f2_b, const f16_t* __restrict__ f3T,
      const float* __restrict__ f3_b, float* __restrict__ out){
  __shared__ __align__(16) char sm[29824];
  f16_t* hf   = (f16_t*)sm;                 // [64][72]   (phase: hf -> z1 read)
  f16_t* z1   = (f16_t*)(sm + 9216);        // [64][136]
  f16_t* z2   = (f16_t*)sm;                 // [64][72]   aliases hf (hf dead)
  float* tbs  = (float*)(sm + 28512);       // above xt halo region
  float* f1bs = (float*)(sm + 28768);
  float* f2bs = (float*)(sm + 29280);
  f16_t* f3s  = (f16_t*)(sm + 29536);
  float* f3bs = (float*)(sm + 29792);
  f16_t* xt   = (f16_t*)sm;                 // [3][66][72] (conv phase) 28512 B

  int tid = threadIdx.x;
  int blk = blockIdx.x;
  int wc = blk & 3, h = (blk >> 2) & 127, b = blk >> 9;
  int w0 = wc*64;
  int t_idx = (int)ext[b*6+3] - 5;

  if (tid < 64) tbs[tid] = tb[t_idx*64 + tid];
  else if (tid < 192) f1bs[tid-64] = f1_b[tid-64];
  else f2bs[tid-192] = f2_b[tid-192];
  if (tid < 128) f3s[tid] = f3T[tid];
  if (tid < 2) f3bs[tid] = f3_b[tid];

  // main interior 64 px: pow2 indexing, only h-bounds check
  for (int f = tid; f < 1536; f += 256){
    int c8 = f & 7, px = (f >> 3) & 63, dy = f >> 9;
    int hh = h - 1 + dy;
    float4 v = {0.f,0.f,0.f,0.f};
    if (hh >= 0 && hh < HH_)
      v = *(const float4*)(x + (((long)b*HH_ + hh)*WW_ + w0 + px)*64 + c8*8);
    *(float4*)(xt + (dy*66 + px + 1)*72 + c8*8) = v;
  }
  if (tid < 48){                            // halo columns pxl = 0 and 65
    int c8 = tid & 7, r = tid >> 3;         // r: 0..5
    int dy = r >> 1, side = r & 1;
    int pxl = side ? 65 : 0;
    int hh = h - 1 + dy, wg = w0 - 1 + pxl;
    float4 v = {0.f,0.f,0.f,0.f};
    if (hh >= 0 && hh < HH_ && wg >= 0 && wg < WW_)
      v = *(const float4*)(x + (((long)b*HH_ + hh)*WW_ + wg)*64 + c8*8);
    *(float4*)(xt + (dy*66 + pxl)*72 + c8*8) = v;
  }
  __syncthreads();

  int lane = tid & 63, wv = tid >> 6;
  int n15 = lane & 15, quad = lane >> 4;
  int n = wv*16 + n15;

  floatx4 acc[4];
  {
    float bias0 = tbs[n];                   // per-thread const -> acc init
    #pragma unroll
    for (int mt = 0; mt < 4; mt++) acc[mt] = (floatx4){bias0,bias0,bias0,bias0};
  }
  const f16_t* wTt = wT + (long)t_idx*36864;
  for (int tap = 0; tap < 9; tap++){
    int dy = tap/3, dx = tap%3;
    const f16_t* wrow = wTt + (tap*64 + wv*16 + n15)*64;
    #pragma unroll
    for (int kc = 0; kc < 2; kc++){
      half8 bfrag = *(const half8*)(wrow + kc*32 + quad*8);
      #pragma unroll
      for (int mt = 0; mt < 4; mt++){
        int p = mt*16 + n15 + dx;
        half8 a = *(const half8*)(xt + (dy*66 + p)*72 + kc*32 + quad*8);
        acc[mt] = __builtin_amdgcn_mfma_f32_16x16x32_f16(a, bfrag, acc[mt], 0,0,0);
      }
    }
  }
  __syncthreads();                           // xt dead
  {
    #pragma unroll
    for (int mt = 0; mt < 4; mt++){
      #pragma unroll
      for (int r = 0; r < 4; r++){
        int m = mt*16 + quad*4 + r;
        hf[m*72 + n] = (f16_t)gelu_f(acc[mt][r]);
      }
    }
  }
  __syncthreads();
  // z1 = gelu(hf . f1^T + f1_b): M=64 N=128 K=64
  #pragma unroll
  for (int nt = 0; nt < 2; nt++){
    int n1 = wv*32 + nt*16 + n15;
    float bias = f1bs[n1];
    half8 bf0 = *(const half8*)(f1T + n1*64 + quad*8);
    half8 bf1 = *(const half8*)(f1T + n1*64 + 32 + quad*8);
    #pragma unroll
    for (int mt = 0; mt < 4; mt++){
      floatx4 c = {bias, bias, bias, bias};
      half8 a0 = *(const half8*)(hf + (mt*16 + n15)*72 + quad*8);
      half8 a1 = *(const half8*)(hf + (mt*16 + n15)*72 + 32 + quad*8);
      c = __builtin_amdgcn_mfma_f32_16x16x32_f16(a0, bf0, c, 0,0,0);
      c = __builtin_amdgcn_mfma_f32_16x16x32_f16(a1, bf1, c, 0,0,0);
      #pragma unroll
      for (int r = 0; r < 4; r++){
        int m = mt*16 + quad*4 + r;
        z1[m*136 + n1] = (f16_t)gelu_f(c[r]);
      }
    }
  }
  __syncthreads();
  // z2 = gelu(z1 . f2^T + f2_b): M=64 N=64 K=128  (z2 overwrites dead hf)
  {
    float bias = f2bs[n];
    half8 bf[4];
    #pragma unroll
    for (int kc = 0; kc < 4; kc++)
      bf[kc] = *(const half8*)(f2T + n*128 + kc*32 + quad*8);
    #pragma unroll
    for (int mt = 0; mt < 4; mt++){
      floatx4 c = {bias, bias, bias, bias};
      #pragma unroll
      for (int kc = 0; kc < 4; kc++){
        half8 a = *(const half8*)(z1 + (mt*16 + n15)*136 + kc*32 + quad*8);
        c = __builtin_amdgcn_mfma_f32_16x16x32_f16(a, bf[kc], c, 0,0,0);
      }
      #pragma unroll
      for (int r = 0; r < 4; r++){
        int m = mt*16 + quad*4 + r;
        z2[m*72 + n] = (f16_t)gelu_f(c[r]);
      }
    }
  }
  __syncthreads();
  // f3: out[px][0..1]
  if (tid < 128){
    int px = tid >> 1, oo = tid & 1;
    const f16_t* zr = z2 + px*72;
    const f16_t* fr = f3s + oo*64;
    float a = f3bs[oo];
    #pragma unroll
    for (int g = 0; g < 8; g++){
      half8 zv = *(const half8*)(zr + g*8);
      half8 wv2 = *(const half8*)(fr + g*8);
#if __has_builtin(__builtin_amdgcn_fdot2)
      #pragma unroll
      for (int q = 0; q < 4; q++){
        half2v za = {zv[2*q], zv[2*q+1]};
        half2v wa = {wv2[2*q], wv2[2*q+1]};
        a = __builtin_amdgcn_fdot2(za, wa, a, false);
      }
#else
      #pragma unroll
      for (int q = 0; q < 8; q++) a += (float)zv[q]*(float)wv2[q];
#endif
    }
    out[(((long)b*HH_ + h)*WW_ + w0 + px)*2 + oo] = a;
  }
}

extern "C" void kernel_launch(void* const* d_in, const int* in_sizes, int n_in,
                              void* d_out, int out_size, void* d_ws, size_t ws_size,
                              hipStream_t stream){
  const float* inp     = (const float*)d_in[0];
  const float* ext     = (const float*)d_in[1];
  const float* enc_w   = (const float*)d_in[2];
  const float* enc_b   = (const float*)d_in[3];
  const float* w1r     = (const float*)d_in[4];
  const float* w1i     = (const float*)d_in[5];
  const float* w2r     = (const float*)d_in[6];
  const float* w2i     = (const float*)d_in[7];
  const float* ws_w    = (const float*)d_in[8];
  const float* ws_b    = (const float*)d_in[9];
  const float* day_emb = (const float*)d_in[10];
  const float* hour_emb= (const float*)d_in[11];
  const float* e1_w    = (const float*)d_in[12];
  const float* e1_b    = (const float*)d_in[13];
  const float* e2_w    = (const float*)d_in[14];
  const float* e2_b    = (const float*)d_in[15];
  const float* tw      = (const float*)d_in[16];
  const float* tb      = (const float*)d_in[17];
  const float* f1_w    = (const float*)d_in[18];
  const float* f1_b    = (const float*)d_in[19];
  const float* f2_w    = (const float*)d_in[20];
  const float* f2_b    = (const float*)d_in[21];
  const float* f3_w    = (const float*)d_in[22];
  const float* f3_b    = (const float*)d_in[23];
  float* outp = (float*)d_out;

  const size_t need = 248652032;
  if (ws_size < need){
    k_diag<<<dim3(1), dim3(64), 0, stream>>>(outp, (float)(ws_size >> 20));
    return;
  }
  char* p = (char*)d_ws;
  f16_t*  x    = (f16_t*)(p);                    // 134217728 B
  float2* fp0  = (float2*)(p + 134217728);       // 25165824 B
  float2* fp1  = (float2*)(p + 159383552);       // 25165824 B
  float2* zi   = (float2*)(p + 184549376);       // 25165824 B
  float*  gate = (float*)(p + 184549376);        // 4 MB, aliases zi (dead till spec)
  float*  gg   = (float*)(p + 209715200);        // 8 KB, in old twf region
  float2* thf  = (float2*)(p + 209739776);       // 24576 B
  float2* thi  = (float2*)(p + 209764352);       // 24576 B
  f16_t*  twzh = (f16_t*)(p + 209788928);        // 16384 B
  f16_t*  wT   = (f16_t*)(p + 209805312);        // 1032192 B
  f16_t*  f1T  = (f16_t*)(p + 210837504);        // 16384 B
  f16_t*  f2T  = (f16_t*)(p + 210853888);        // 16384 B
  f16_t*  f3T  = (f16_t*)(p + 210870272);        // 256 B
  float2* wmix = (float2*)(p + 210870528);       // 37748736 B
  f16_t*  twA  = (f16_t*)(p + 248619264);        // 32768 B

  k_prep<<<dim3(1009), dim3(256), 0, stream>>>(gg, thf, thi, twzh,
      f1_w, f2_w, f3_w, f1T, f2T, f3T, tw, wT, w1r, w1i, w2r, w2i, wmix, twA,
      ext, day_emb, hour_emb, e1_w, e1_b);
  k_gate<<<dim3(128), dim3(256), 0, stream>>>(gg, e2_w, e2_b, gate);
  k_gxdft<<<dim3(4096), dim3(256), 0, stream>>>(gate, inp, enc_w, enc_b,
                                                twA, x, fp0, fp1);
  for (int l = 0; l < 4; l++){
    k_spec<<<dim3(384), dim3(256), 0, stream>>>(fp0, fp1, 1,
                                                thf, thi, wmix, l, zi);
    k_iw_mfma<<<dim3(8192), dim3(256), 0, stream>>>(x, zi, ws_w, ws_b, twzh,
                       twA, fp0, fp1, l, (l < 3) ? 1 : 0, (l < 3) ? 1 : 0);
  }
  k_conv_head<<<dim3(16384), dim3(256), 0, stream>>>(x, ext, wT, tb,
                     f1T, f1_b, f2T, f2_b, f3T, f3_b, outp);
}

// Round 10
// 1196.023 us; speedup vs baseline: 1.0967x; 1.0022x over previous
//
#include <hip/hip_runtime.h>
#include <math.h>

#define BB 32
#define HH_ 128
#define WW_ 256

typedef _Float16 f16_t;
typedef _Float16 half8 __attribute__((ext_vector_type(8)));
typedef _Float16 half4 __attribute__((ext_vector_type(4)));
typedef _Float16 half2v __attribute__((ext_vector_type(2)));
typedef float floatx4 __attribute__((ext_vector_type(4)));

// Branch-free fast gelu, relu-form (A-S 7.1.26, |erf err| <= 1.5e-7).
__device__ __forceinline__ float gelu_f(float v){
  float av = __builtin_fabsf(v);
  float s = av * 0.70710678118654752f;
  float k = __builtin_amdgcn_rcpf(__builtin_fmaf(0.3275911f, s, 1.0f));
  float p = __builtin_fmaf(1.061405429f, k, -1.453152027f);
  p = __builtin_fmaf(p, k, 1.421413741f);
  p = __builtin_fmaf(p, k, -0.284496736f);
  p = __builtin_fmaf(p, k, 0.254829592f);
  p = p * k;
  float e = __expf(-s * s);
  float q = 0.5f * av * p;
  return __builtin_fmaf(-q, e, fmaxf(v, 0.f));
}

// Exact-reduced DFT twiddle: angle = sgn * 2*pi * (prod mod N) / N.
__device__ __forceinline__ float2 twiddle(int prod, int N, float sgn){
  int m = prod & (N - 1);
  float a = sgn * (6.2831853071795864769f / (float)N) * (float)m;
  return make_float2(cosf(a), sinf(a));
}

__global__ void k_diag(float* out, float v){ out[threadIdx.x] = v; }

// ---- merged prep: [0,113) tables+head-f16; [113,169) wprep;
//      [169,937) mixprep; [937,1001) twA; [1001,1009) ext-MLP g vector -------
__global__ __launch_bounds__(256) void k_prep(
      float* gg, float2* thf, float2* thi, f16_t* twzh,
      const float* __restrict__ f1_w, const float* __restrict__ f2_w,
      const float* __restrict__ f3_w, f16_t* f1T, f16_t* f2T, f16_t* f3T,
      const float* __restrict__ tw, f16_t* __restrict__ wT,
      const float* __restrict__ w1r, const float* __restrict__ w1i,
      const float* __restrict__ w2r, const float* __restrict__ w2i,
      float2* __restrict__ wmix, f16_t* __restrict__ twA,
      const float* __restrict__ ext, const float* __restrict__ day_emb,
      const float* __restrict__ hour_emb, const float* __restrict__ e1_w,
      const float* __restrict__ e1_b){
  __shared__ __align__(16) char smp[53248];
  int blk = blockIdx.x, tid = threadIdx.x;
  if (blk < 113){
    int t = blk*256 + tid;
    if (t < 3072){
      // spare slot
    } else if (t < 6144){                // forward h-DFT: [h][j]
      int f = t-3072; int h = f/24, j = f%24;
      int kx = (j<12)? j : j+104;
      thf[f] = twiddle(h*kx, 128, -1.f);
    } else if (t < 9216){                // inverse h (includes 1/128)
      int f = t-6144; int h = f/24, j = f%24;
      int kx = (j<12)? j : j+104;
      float2 c = twiddle(h*kx, 128, 1.f);
      thi[f] = make_float2(c.x*0.0078125f, c.y*0.0078125f);
    } else if (t < 12288){               // inverse w (c2r) coefs, f16
      int f = t-9216; int w = f/12, ky = f%12;
      float2 c = twiddle(w*ky, 256, 1.f);
      float s = (ky==0)? 0.00390625f : 0.0078125f;   // (1 or 2)/256
      twzh[w*32 + ky]      = (f16_t)( s*c.x);
      twzh[w*32 + 12 + ky] = (f16_t)(-s*c.y);
      if (ky < 8) twzh[w*32 + 24 + ky] = (f16_t)0.f;
    } else {
      int t2 = t - 12288;                // head weights -> f16
      if (t2 < 8192) f1T[t2] = (f16_t)f1_w[t2];
      else if (t2 < 16384) f2T[t2-8192] = (f16_t)f2_w[t2-8192];
      else if (t2 < 16512) f3T[t2-16384] = (f16_t)f3_w[t2-16384];
    }
  } else if (blk < 169){                 // conv weight transpose via LDS
    float* s = (float*)smp;              // [o16][c][tap]
    int b2 = blk - 113;
    int og = b2 & 3, tt = b2 >> 2;
    const float* src = tw + (long)tt*36864 + og*9216;
    for (int f = tid; f < 9216; f += 256) s[f] = src[f];
    __syncthreads();
    for (int f = tid; f < 9216; f += 256){
      int c = f & 63; int r = f >> 6;
      int o16 = r % 16, tap = r / 16;
      float v = s[(o16*64 + c)*9 + tap];
      wT[(((long)tt*9 + tap)*64 + og*16 + o16)*64 + c] = (f16_t)v;
    }
  } else if (blk < 937){                 // spectral weight transpose via LDS
    float* sr = (float*)smp;             // 6656 f
    float* si = (float*)(smp + 26624);   // 6656 f
    int b2 = blk - 169;                  // < 768
    int ig  = b2 & 7;
    int kx  = (b2 >> 3) % 12;
    int sel = (b2 / 96) & 1;
    int l   = b2 / 192;
    const float* wr = sel ? w2r : w1r;
    const float* wi = sel ? w2i : w1i;
    for (int f = tid; f < 6144; f += 256){
      int i8 = f / 768; int rem = f % 768;
      int o = rem / 12, ky = rem % 12;
      long addr = (((long)l*64 + ig*8 + i8)*64 + o)*144 + kx*12 + ky;
      sr[(i8*64 + o)*13 + ky] = wr[addr];
      si[(i8*64 + o)*13 + ky] = wi[addr];
    }
    __syncthreads();
    int j = sel ? (kx + 12) : kx;
    for (int f = tid; f < 6144; f += 256){
      int o = f & 63; int r = f >> 6;
      int ky = r % 12, i8 = r / 12;
      int sidx = (i8*64 + o)*13 + ky;
      wmix[(((long)l*288 + j*12 + ky))*4096 + (ig*8 + i8)*64 + o] =
          make_float2(sr[sidx], si[sidx]);
    }
  } else if (blk < 1001){                // twA[half][hl][32 m][128 k] f16
    int t = (blk - 937)*256 + tid;       // < 16384
    int halfi = t >> 13, r = t & 8191;
    int hl = r >> 12, r2 = r & 4095;
    int m = r2 >> 7, k = r2 & 127;
    f16_t v = (f16_t)0.f;
    if (m < 24){
      int ky = m >> 1, ri = m & 1;
      int w = halfi*128 + k;
      float2 c = twiddle(w*ky, 256, -1.f);
      float t32 = ri ? c.y : c.x;
      f16_t hi = (f16_t)t32;
      v = hl ? (f16_t)(t32 - (float)hi) : hi;
    }
    twA[t] = v;
  } else {                               // ext MLP g: gg[32 b][64 j]
    int b2 = blk - 1001;                 // 0..7
    int bloc = tid >> 6, j = tid & 63;
    int b = b2*4 + bloc;
    const float* e = ext + b*6;
    float emb[6];
    emb[0] = e[0];
    int d  = (int)e[2];
    emb[1] = day_emb[d*2];  emb[2] = day_emb[d*2+1];
    int hr = (int)e[3];
    emb[3] = hour_emb[hr*3]; emb[4] = hour_emb[hr*3+1]; emb[5] = hour_emb[hr*3+2];
    float acc = e1_b[j];
    #pragma unroll
    for (int k = 0; k < 6; k++) acc += emb[k]*e1_w[j*6+k];
    gg[b*64 + j] = gelu_f(acc);
  }
}

// ---- gate precompute: gate[b][hw] = gelu(g[b] . e2_w[hw] + e2_b[hw]) --------
__global__ __launch_bounds__(256) void k_gate(const float* __restrict__ gg,
      const float* __restrict__ e2_w, const float* __restrict__ e2_b,
      float* __restrict__ gate){
  __shared__ float gs[2048];
  int tid = threadIdx.x;
  for (int f = tid; f < 2048; f += 256) gs[f] = gg[f];
  __syncthreads();
  long hw = (long)blockIdx.x*256 + tid;
  const float4* wrow = (const float4*)(e2_w + hw*64);
  float4 w[16];
  #pragma unroll
  for (int k = 0; k < 16; k++) w[k] = wrow[k];
  float eb2 = e2_b[hw];
  for (int b = 0; b < 32; b++){
    const float* g = gs + b*64;
    float acc = eb2;
    #pragma unroll
    for (int k = 0; k < 16; k++){
      float4 v = w[k];
      acc += v.x*g[4*k] + v.y*g[4*k+1] + v.z*g[4*k+2] + v.w*g[4*k+3];
    }
    gate[(long)b*32768 + hw] = gelu_f(acc);
  }
}

// ---- encoder + layer-0 w-DFT (MFMA), block=(b,h) row; gate precomputed -----
__global__ __launch_bounds__(256) void k_gxdft(
      const float* __restrict__ gate, const float* __restrict__ inp,
      const float* __restrict__ enc_w, const float* __restrict__ enc_b,
      const f16_t* __restrict__ twA, f16_t* __restrict__ x,
      float2* __restrict__ fp0, float2* __restrict__ fp1){
  __shared__ __align__(16) char sm[41984];
  f16_t* Obt   = (f16_t*)sm;              // [64 c][274 w-pad]  35072 B
  float* gvs   = (float*)(sm + 35072);    // 256
  float4* ips  = (float4*)(sm + 36096);   // 256 float4
  float* ew    = (float*)(sm + 40448);    // 320
  float* eb    = (float*)(sm + 41728);    // 64
  int tid = threadIdx.x;
  int bh = blockIdx.x;                    // b*128 + h
  int b = bh >> 7, h = bh & 127;
  if (tid < 64) eb[tid] = enc_b[tid];
  for (int f = tid; f < 320; f += 256) ew[f] = enc_w[f];
  {                                        // gate load + input stage per pixel
    int px = tid;
    long hw = (long)h*256 + px;
    gvs[px] = gate[(long)b*32768 + hw];
    ips[px] = *(const float4*)(inp + ((long)b*32768 + hw)*4);
  }
  __syncthreads();
  int lane = tid & 63, wv = tid >> 6;
  {                                        // encoder: thread = (c, 64-px group)
    int c = lane, wg = wv;
    const float* wr2 = ew + c*5;
    float w0 = wr2[0], w1 = wr2[1], w2 = wr2[2], w3 = wr2[3], w4 = wr2[4];
    float ebc = eb[c];
    f16_t* xo = x + ((long)bh*256 + wg*64)*64 + c;
    #pragma unroll 2
    for (int g8 = 0; g8 < 8; g8++){
      half8 hv;
      #pragma unroll
      for (int e2 = 0; e2 < 8; e2++){
        int i = g8*8 + e2;
        float4 ip = ips[wg*64 + i];
        float gv = gvs[wg*64 + i];
        float v = ebc + ip.x*w0 + ip.y*w1 + ip.z*w2 + ip.w*w3 + gv*w4;
        f16_t hval = (f16_t)v;
        hv[e2] = hval;
        xo[i*64] = hval;                   // coalesced across lanes (same i)
      }
      *(half8*)(Obt + c*274 + wg*64 + g8*8) = hv;
    }
  }
  __syncthreads();                         // Obt ready
  int n15 = lane & 15, quad = lane >> 4;
  int n = wv*16 + n15;
  #pragma unroll
  for (int half = 0; half < 2; half++){
    half8 bfr2[4];
    #pragma unroll
    for (int ks = 0; ks < 4; ks++)
      bfr2[ks] = *(const half8*)(Obt + n*274 + half*128 + ks*32 + quad*8);
    floatx4 dacc[2];
    dacc[0] = (floatx4){0.f,0.f,0.f,0.f};
    dacc[1] = (floatx4){0.f,0.f,0.f,0.f};
    #pragma unroll
    for (int hl = 0; hl < 2; hl++){
      #pragma unroll
      for (int mt = 0; mt < 2; mt++){
        #pragma unroll
        for (int ks = 0; ks < 4; ks++){
          half8 a = *(const half8*)(twA + half*8192 + hl*4096
                                    + (mt*16 + n15)*128 + ks*32 + quad*8);
          dacc[mt] = __builtin_amdgcn_mfma_f32_16x16x32_f16(a, bfr2[ks],
                                                            dacc[mt], 0,0,0);
        }
      }
    }
    float2* dst = half ? fp1 : fp0;
    #pragma unroll
    for (int mt = 0; mt < 2; mt++){
      int m0 = mt*16 + quad*4;
      if (m0 < 24){
        int ky0 = m0 >> 1;
        dst[(long)bh*768 + ky0*64 + n]     = make_float2(dacc[mt][0], dacc[mt][1]);
        dst[(long)bh*768 + (ky0+1)*64 + n] = make_float2(dacc[mt][2], dacc[mt][3]);
      }
    }
  }
}

// ---- FUSED spectral chain: dft_h + mode-mix + ifft_h, block=(b,ky) ---------
__global__ __launch_bounds__(256) void k_spec(const float2* __restrict__ s0,
      const float2* __restrict__ s1, int dual, const float2* __restrict__ thf_g,
      const float2* __restrict__ thi_g, const float2* __restrict__ wmix,
      int layer, float2* __restrict__ zi){
  __shared__ __align__(16) char sm[40960];
  float2* th  = (float2*)sm;            // 3072 f2: thf (A) then thi (C)
  float2* xch = (float2*)(sm + 24576);  // 2048 f2 staging (A)
  float2* mixL= (float2*)(sm + 24576);  // [24 j][64 o] (B->C), aliases xch
  int tid = threadIdx.x;
  int b = blockIdx.x / 12, ky = blockIdx.x % 12;
  int wv = tid >> 6, lane = tid & 63;
  for (int f = tid; f < 3072; f += 256) th[f] = thf_g[f];
  // Stage A: h-DFT. acc[q] = xft[j=q*4+wv][c=lane]
  float2 acc[6];
  #pragma unroll
  for (int q = 0; q < 6; q++) acc[q] = make_float2(0.f, 0.f);
  long base = (long)b*98304 + ky*64;
  for (int ch = 0; ch < 4; ch++){
    __syncthreads();
    for (int f = tid; f < 2048; f += 256){
      int hh = f >> 6, c = f & 63;
      long idx = base + (long)(ch*32 + hh)*768 + c;
      float2 v = s0[idx];
      if (dual){ float2 u = s1[idx]; v.x += u.x; v.y += u.y; }
      xch[f] = v;
    }
    __syncthreads();
    for (int hh = 0; hh < 32; hh++){
      float2 v = xch[hh*64 + lane];
      int hg = ch*32 + hh;
      #pragma unroll
      for (int q = 0; q < 6; q++){
        float2 t = th[hg*24 + q*4 + wv];
        acc[q].x += t.x*v.x - t.y*v.y;
        acc[q].y += t.x*v.y + t.y*v.x;
      }
    }
  }
  __syncthreads();                      // A done: xch & thf dead after here
  for (int f = tid; f < 3072; f += 256) th[f] = thi_g[f];   // stage thi
  // Stage B: mode-mix, register-resident via shfl
  float2 mout[6];
  #pragma unroll
  for (int q = 0; q < 6; q++){
    int j = q*4 + wv;
    const float2* wj = wmix + (((long)layer*288 + j*12 + ky))*4096;
    float re = 0.f, im = 0.f;
    #pragma unroll 8
    for (int i = 0; i < 64; i++){
      float vr = __shfl(acc[q].x, i);
      float vi = __shfl(acc[q].y, i);
      float2 ww = wj[i*64 + lane];
      re += vr*ww.x - vi*ww.y;
      im += vr*ww.y + vi*ww.x;
    }
    mout[q] = make_float2(re, im);
  }
  #pragma unroll
  for (int q = 0; q < 6; q++) mixL[(q*4 + wv)*64 + lane] = mout[q];
  __syncthreads();                      // mixL + thi ready
  // Stage C: inverse h-DFT
  float2 cr[24];
  #pragma unroll
  for (int j = 0; j < 24; j++) cr[j] = mixL[j*64 + lane];
  for (int qq = 0; qq < 32; qq++){
    int h = qq*4 + wv;
    float re = 0.f, im = 0.f;
    #pragma unroll
    for (int j = 0; j < 24; j++){
      float2 t = th[h*24 + j];
      re += t.x*cr[j].x - t.y*cr[j].y;
      im += t.x*cr[j].y + t.y*cr[j].x;
    }
    zi[((long)b*128 + h)*768 + ky*64 + lane] = make_float2(re, im);
  }
}

// ------- MFMA: inverse-w + skip + bias + (gelu), in place on x,
//         fused next-layer partial w-DFT via MFMA (twA hi/lo) ----------------
// dodft B-fragments via intra-wave __shfl of the packed epilogue values
// (pixel P=ks*32+quad*8+j lives in lanes 2(quad&1)*16+n15 / +16 of the SAME
// wave; mt_src=2ks+(quad>>1), r=j&3). Removes the Obt LDS round-trip and 2 of
// 3 barriers: after the staging barrier, waves run fully decoupled.
__global__ __launch_bounds__(256) void k_iw_mfma(f16_t* __restrict__ x,
      const float2* __restrict__ zi, const float* __restrict__ ws_w,
      const float* __restrict__ ws_b, const f16_t* __restrict__ twzh,
      const f16_t* __restrict__ twA, float2* __restrict__ fp0,
      float2* __restrict__ fp1, int layer, int act, int dodft){
  __shared__ __align__(16) char sm[28672];
  f16_t* A1  = (f16_t*)sm;                  // [128 px][72] x channels
  f16_t* Bzh = (f16_t*)(sm + 18432);        // [64 o][40]
  f16_t* Bzl = (f16_t*)(sm + 23552);        // [64 o][40]
  int tid = threadIdx.x;
  int blk = blockIdx.x;
  int half = blk & 1;
  long bh = blk >> 1;                       // b*128 + h
  int w0 = half*128;
  const f16_t* xrow = x + (bh*256 + w0)*64;
  for (int f = tid; f < 1024; f += 256){    // A1: 128 px x 8 chunks, 16B
    int px = f >> 3, c8 = f & 7;
    *(float4*)(A1 + px*72 + c8*8) = *(const float4*)(xrow + px*64 + c8*8);
  }
  const float2* zrow = zi + bh*768;
  for (int f = tid; f < 768; f += 256){     // z hi/lo split
    int o = f & 63, ky = f >> 6;
    float2 v = zrow[ky*64 + o];
    f16_t hr = (f16_t)v.x; f16_t hi_ = (f16_t)v.y;
    Bzh[o*40 + ky]      = hr;
    Bzh[o*40 + 12 + ky] = hi_;
    Bzl[o*40 + ky]      = (f16_t)(v.x - (float)hr);
    Bzl[o*40 + 12 + ky] = (f16_t)(v.y - (float)hi_);
  }
  if (tid < 64){                            // zero cols 24..31 (read by quad 3)
    float4 z4 = {0.f,0.f,0.f,0.f};
    *(float4*)(Bzh + tid*40 + 24) = z4;
    *(float4*)(Bzl + tid*40 + 24) = z4;
  }
  __syncthreads();                          // the ONLY barrier
  int lane = tid & 63, wv = tid >> 6;
  int n15 = lane & 15, quad = lane >> 4;
  int n = wv*16 + n15;
  // B fragments: ws from global f32 (L2-hot, 16KB/layer), z from LDS
  half8 bws[2];
  {
    const float* wsl = ws_w + ((long)layer*64 + n)*64;
    #pragma unroll
    for (int kc = 0; kc < 2; kc++){
      float4 u0 = *(const float4*)(wsl + kc*32 + quad*8);
      float4 u1 = *(const float4*)(wsl + kc*32 + quad*8 + 4);
      half8 hb;
      hb[0]=(f16_t)u0.x; hb[1]=(f16_t)u0.y; hb[2]=(f16_t)u0.z; hb[3]=(f16_t)u0.w;
      hb[4]=(f16_t)u1.x; hb[5]=(f16_t)u1.y; hb[6]=(f16_t)u1.z; hb[7]=(f16_t)u1.w;
      bws[kc] = hb;
    }
  }
  float bias = ws_b[layer*64 + n];
  half8 bzh = *(const half8*)(Bzh + n*40 + quad*8);
  half8 bzl = *(const half8*)(Bzl + n*40 + quad*8);
  floatx4 acc[8];
  #pragma unroll
  for (int mt = 0; mt < 8; mt++){
    floatx4 c = {bias, bias, bias, bias};   // bias folded into accumulator
    half8 ax0 = *(const half8*)(A1 + (mt*16 + n15)*72 + quad*8);
    half8 ax1 = *(const half8*)(A1 + (mt*16 + n15)*72 + 32 + quad*8);
    half8 atw = *(const half8*)(twzh + (w0 + mt*16 + n15)*32 + quad*8);
    c = __builtin_amdgcn_mfma_f32_16x16x32_f16(ax0, bws[0], c, 0,0,0);
    c = __builtin_amdgcn_mfma_f32_16x16x32_f16(ax1, bws[1], c, 0,0,0);
    c = __builtin_amdgcn_mfma_f32_16x16x32_f16(atw, bzh,    c, 0,0,0);
    c = __builtin_amdgcn_mfma_f32_16x16x32_f16(atw, bzl,    c, 0,0,0);
    acc[mt] = c;
  }
  // epilogue: gelu + coalesced scalar store + pack for shfl exchange
  f16_t* xo = x + (bh*256 + w0)*64;
  uint2 pk[8];
  #pragma unroll
  for (int mt = 0; mt < 8; mt++){
    half4 hv;
    #pragma unroll
    for (int r = 0; r < 4; r++){
      float v = acc[mt][r];
      if (act) v = gelu_f(v);
      hv[r] = (f16_t)v;
      xo[(mt*16 + quad*4 + r)*64 + n] = hv[r];
    }
    pk[mt] = __builtin_bit_cast(uint2, hv);
  }
  if (dodft){                                // next-layer w-DFT, B via shfl
    int qhalf = quad >> 1;
    int srcA = ((quad & 1) << 5) + n15;       // lane of quad_src = 2*(quad&1)
    int srcB = srcA + 16;
    half8 bfr2[4];
    #pragma unroll
    for (int ks = 0; ks < 4; ks++){
      uint2 lo  = pk[2*ks];
      uint2 hi2 = pk[2*ks + 1];
      unsigned w0a_l = (unsigned)__shfl((int)lo.x,  srcA, 64);
      unsigned w1a_l = (unsigned)__shfl((int)lo.y,  srcA, 64);
      unsigned w0a_h = (unsigned)__shfl((int)hi2.x, srcA, 64);
      unsigned w1a_h = (unsigned)__shfl((int)hi2.y, srcA, 64);
      unsigned w0b_l = (unsigned)__shfl((int)lo.x,  srcB, 64);
      unsigned w1b_l = (unsigned)__shfl((int)lo.y,  srcB, 64);
      unsigned w0b_h = (unsigned)__shfl((int)hi2.x, srcB, 64);
      unsigned w1b_h = (unsigned)__shfl((int)hi2.y, srcB, 64);
      uint4 u;
      u.x = qhalf ? w0a_h : w0a_l;
      u.y = qhalf ? w1a_h : w1a_l;
      u.z = qhalf ? w0b_h : w0b_l;
      u.w = qhalf ? w1b_h : w1b_l;
      bfr2[ks] = __builtin_bit_cast(half8, u);
    }
    floatx4 dacc[2];
    dacc[0] = (floatx4){0.f,0.f,0.f,0.f};
    dacc[1] = (floatx4){0.f,0.f,0.f,0.f};
    #pragma unroll
    for (int hl = 0; hl < 2; hl++){
      #pragma unroll
      for (int mt = 0; mt < 2; mt++){
        #pragma unroll
        for (int ks = 0; ks < 4; ks++){
          half8 a = *(const half8*)(twA + half*8192 + hl*4096
                                    + (mt*16 + n15)*128 + ks*32 + quad*8);
          dacc[mt] = __builtin_amdgcn_mfma_f32_16x16x32_f16(a, bfr2[ks],
                                                            dacc[mt], 0,0,0);
        }
      }
    }
    float2* dst = half ? fp1 : fp0;
    #pragma unroll
    for (int mt = 0; mt < 2; mt++){
      int m0 = mt*16 + quad*4;
      if (m0 < 24){
        int ky0 = m0 >> 1;
        dst[bh*768 + ky0*64 + n]     = make_float2(dacc[mt][0], dacc[mt][1]);
        dst[bh*768 + (ky0+1)*64 + n] = make_float2(dacc[mt][2], dacc[mt][3]);
      }
    }
  }
}

// ------- MFMA conv 3x3 (per-batch weights) + gelu + head, fused; 64-px tiles -
__global__ __launch_bounds__(256) void k_conv_head(const f16_t* __restrict__ x,
      const float* __restrict__ ext, const f16_t* __restrict__ wT,
      const float* __restrict__ tb, const f16_t* __restrict__ f1T,
      const float* __restrict__ f1_b, const f16_t* __restrict__ f2T,
      const float* __restrict__ f2_b, const f16_t* __restrict__ f3T,
      const float* __restrict__ f3_b, float* __restrict__ out){
  __shared__ __align__(16) char sm[29824];
  f16_t* hf   = (f16_t*)sm;                 // [64][72]   (phase: hf -> z1 read)
  f16_t* z1   = (f16_t*)(sm + 9216);        // [64][136]
  f16_t* z2   = (f16_t*)sm;                 // [64][72]   aliases hf (hf dead)
  float* tbs  = (float*)(sm + 28512);       // above xt halo region
  float* f1bs = (float*)(sm + 28768);
  float* f2bs = (float*)(sm + 29280);
  f16_t* f3s  = (f16_t*)(sm + 29536);
  float* f3bs = (float*)(sm + 29792);
  f16_t* xt   = (f16_t*)sm;                 // [3][66][72] (conv phase) 28512 B

  int tid = threadIdx.x;
  int blk = blockIdx.x;
  int wc = blk & 3, h = (blk >> 2) & 127, b = blk >> 9;
  int w0 = wc*64;
  int t_idx = (int)ext[b*6+3] - 5;

  if (tid < 64) tbs[tid] = tb[t_idx*64 + tid];
  else if (tid < 192) f1bs[tid-64] = f1_b[tid-64];
  else f2bs[tid-192] = f2_b[tid-192];
  if (tid < 128) f3s[tid] = f3T[tid];
  if (tid < 2) f3bs[tid] = f3_b[tid];

  // main interior 64 px: pow2 indexing, only h-bounds check
  for (int f = tid; f < 1536; f += 256){
    int c8 = f & 7, px = (f >> 3) & 63, dy = f >> 9;
    int hh = h - 1 + dy;
    float4 v = {0.f,0.f,0.f,0.f};
    if (hh >= 0 && hh < HH_)
      v = *(const float4*)(x + (((long)b*HH_ + hh)*WW_ + w0 + px)*64 + c8*8);
    *(float4*)(xt + (dy*66 + px + 1)*72 + c8*8) = v;
  }
  if (tid < 48){                            // halo columns pxl = 0 and 65
    int c8 = tid & 7, r = tid >> 3;         // r: 0..5
    int dy = r >> 1, side = r & 1;
    int pxl = side ? 65 : 0;
    int hh = h - 1 + dy, wg = w0 - 1 + pxl;
    float4 v = {0.f,0.f,0.f,0.f};
    if (hh >= 0 && hh < HH_ && wg >= 0 && wg < WW_)
      v = *(const float4*)(x + (((long)b*HH_ + hh)*WW_ + wg)*64 + c8*8);
    *(float4*)(xt + (dy*66 + pxl)*72 + c8*8) = v;
  }
  __syncthreads();

  int lane = tid & 63, wv = tid >> 6;
  int n15 = lane & 15, quad = lane >> 4;
  int n = wv*16 + n15;

  floatx4 acc[4];
  {
    float bias0 = tbs[n];                   // per-thread const -> acc init
    #pragma unroll
    for (int mt = 0; mt < 4; mt++) acc[mt] = (floatx4){bias0,bias0,bias0,bias0};
  }
  const f16_t* wTt = wT + (long)t_idx*36864;
  for (int tap = 0; tap < 9; tap++){
    int dy = tap/3, dx = tap%3;
    const f16_t* wrow = wTt + (tap*64 + wv*16 + n15)*64;
    #pragma unroll
    for (int kc = 0; kc < 2; kc++){
      half8 bfrag = *(const half8*)(wrow + kc*32 + quad*8);
      #pragma unroll
      for (int mt = 0; mt < 4; mt++){
        int p = mt*16 + n15 + dx;
        half8 a = *(const half8*)(xt + (dy*66 + p)*72 + kc*32 + quad*8);
        acc[mt] = __builtin_amdgcn_mfma_f32_16x16x32_f16(a, bfrag, acc[mt], 0,0,0);
      }
    }
  }
  __syncthreads();                           // xt dead
  {
    #pragma unroll
    for (int mt = 0; mt < 4; mt++){
      #pragma unroll
      for (int r = 0; r < 4; r++){
        int m = mt*16 + quad*4 + r;
        hf[m*72 + n] = (f16_t)gelu_f(acc[mt][r]);
      }
    }
  }
  __syncthreads();
  // z1 = gelu(hf . f1^T + f1_b): M=64 N=128 K=64
  #pragma unroll
  for (int nt = 0; nt < 2; nt++){
    int n1 = wv*32 + nt*16 + n15;
    float bias = f1bs[n1];
    half8 bf0 = *(const half8*)(f1T + n1*64 + quad*8);
    half8 bf1 = *(const half8*)(f1T + n1*64 + 32 + quad*8);
    #pragma unroll
    for (int mt = 0; mt < 4; mt++){
      floatx4 c = {bias, bias, bias, bias};
      half8 a0 = *(const half8*)(hf + (mt*16 + n15)*72 + quad*8);
      half8 a1 = *(const half8*)(hf + (mt*16 + n15)*72 + 32 + quad*8);
      c = __builtin_amdgcn_mfma_f32_16x16x32_f16(a0, bf0, c, 0,0,0);
      c = __builtin_amdgcn_mfma_f32_16x16x32_f16(a1, bf1, c, 0,0,0);
      #pragma unroll
      for (int r = 0; r < 4; r++){
        int m = mt*16 + quad*4 + r;
        z1[m*136 + n1] = (f16_t)gelu_f(c[r]);
      }
    }
  }
  __syncthreads();
  // z2 = gelu(z1 . f2^T + f2_b): M=64 N=64 K=128  (z2 overwrites dead hf)
  {
    float bias = f2bs[n];
    half8 bf[4];
    #pragma unroll
    for (int kc = 0; kc < 4; kc++)
      bf[kc] = *(const half8*)(f2T + n*128 + kc*32 + quad*8);
    #pragma unroll
    for (int mt = 0; mt < 4; mt++){
      floatx4 c = {bias, bias, bias, bias};
      #pragma unroll
      for (int kc = 0; kc < 4; kc++){
        half8 a = *(const half8*)(z1 + (mt*16 + n15)*136 + kc*32 + quad*8);
        c = __builtin_amdgcn_mfma_f32_16x16x32_f16(a, bf[kc], c, 0,0,0);
      }
      #pragma unroll
      for (int r = 0; r < 4; r++){
        int m = mt*16 + quad*4 + r;
        z2[m*72 + n] = (f16_t)gelu_f(c[r]);
      }
    }
  }
  __syncthreads();
  // f3: out[px][0..1]
  if (tid < 128){
    int px = tid >> 1, oo = tid & 1;
    const f16_t* zr = z2 + px*72;
    const f16_t* fr = f3s + oo*64;
    float a = f3bs[oo];
    #pragma unroll
    for (int g = 0; g < 8; g++){
      half8 zv = *(const half8*)(zr + g*8);
      half8 wv2 = *(const half8*)(fr + g*8);
#if __has_builtin(__builtin_amdgcn_fdot2)
      #pragma unroll
      for (int q = 0; q < 4; q++){
        half2v za = {zv[2*q], zv[2*q+1]};
        half2v wa = {wv2[2*q], wv2[2*q+1]};
        a = __builtin_amdgcn_fdot2(za, wa, a, false);
      }
#else
      #pragma unroll
      for (int q = 0; q < 8; q++) a += (float)zv[q]*(float)wv2[q];
#endif
    }
    out[(((long)b*HH_ + h)*WW_ + w0 + px)*2 + oo] = a;
  }
}

extern "C" void kernel_launch(void* const* d_in, const int* in_sizes, int n_in,
                              void* d_out, int out_size, void* d_ws, size_t ws_size,
                              hipStream_t stream){
  const float* inp     = (const float*)d_in[0];
  const float* ext     = (const float*)d_in[1];
  const float* enc_w   = (const float*)d_in[2];
  const float* enc_b   = (const float*)d_in[3];
  const float* w1r     = (const float*)d_in[4];
  const float* w1i     = (const float*)d_in[5];
  const float* w2r     = (const float*)d_in[6];
  const float* w2i     = (const float*)d_in[7];
  const float* ws_w    = (const float*)d_in[8];
  const float* ws_b    = (const float*)d_in[9];
  const float* day_emb = (const float*)d_in[10];
  const float* hour_emb= (const float*)d_in[11];
  const float* e1_w    = (const float*)d_in[12];
  const float* e1_b    = (const float*)d_in[13];
  const float* e2_w    = (const float*)d_in[14];
  const float* e2_b    = (const float*)d_in[15];
  const float* tw      = (const float*)d_in[16];
  const float* tb      = (const float*)d_in[17];
  const float* f1_w    = (const float*)d_in[18];
  const float* f1_b    = (const float*)d_in[19];
  const float* f2_w    = (const float*)d_in[20];
  const float* f2_b    = (const float*)d_in[21];
  const float* f3_w    = (const float*)d_in[22];
  const float* f3_b    = (const float*)d_in[23];
  float* outp = (float*)d_out;

  const size_t need = 248652032;
  if (ws_size < need){
    k_diag<<<dim3(1), dim3(64), 0, stream>>>(outp, (float)(ws_size >> 20));
    return;
  }
  char* p = (char*)d_ws;
  f16_t*  x    = (f16_t*)(p);                    // 134217728 B
  float2* fp0  = (float2*)(p + 134217728);       // 25165824 B
  float2* fp1  = (float2*)(p + 159383552);       // 25165824 B
  float2* zi   = (float2*)(p + 184549376);       // 25165824 B
  float*  gate = (float*)(p + 184549376);        // 4 MB, aliases zi (dead till spec)
  float*  gg   = (float*)(p + 209715200);        // 8 KB, in old twf region
  float2* thf  = (float2*)(p + 209739776);       // 24576 B
  float2* thi  = (float2*)(p + 209764352);       // 24576 B
  f16_t*  twzh = (f16_t*)(p + 209788928);        // 16384 B
  f16_t*  wT   = (f16_t*)(p + 209805312);        // 1032192 B
  f16_t*  f1T  = (f16_t*)(p + 210837504);        // 16384 B
  f16_t*  f2T  = (f16_t*)(p + 210853888);        // 16384 B
  f16_t*  f3T  = (f16_t*)(p + 210870272);        // 256 B
  float2* wmix = (float2*)(p + 210870528);       // 37748736 B
  f16_t*  twA  = (f16_t*)(p + 248619264);        // 32768 B

  k_prep<<<dim3(1009), dim3(256), 0, stream>>>(gg, thf, thi, twzh,
      f1_w, f2_w, f3_w, f1T, f2T, f3T, tw, wT, w1r, w1i, w2r, w2i, wmix, twA,
      ext, day_emb, hour_emb, e1_w, e1_b);
  k_gate<<<dim3(128), dim3(256), 0, stream>>>(gg, e2_w, e2_b, gate);
  k_gxdft<<<dim3(4096), dim3(256), 0, stream>>>(gate, inp, enc_w, enc_b,
                                                twA, x, fp0, fp1);
  for (int l = 0; l < 4; l++){
    k_spec<<<dim3(384), dim3(256), 0, stream>>>(fp0, fp1, 1,
                                                thf, thi, wmix, l, zi);
    k_iw_mfma<<<dim3(8192), dim3(256), 0, stream>>>(x, zi, ws_w, ws_b, twzh,
                       twA, fp0, fp1, l, (l < 3) ? 1 : 0, (l < 3) ? 1 : 0);
  }
  k_conv_head<<<dim3(16384), dim3(256), 0, stream>>>(x, ext, wT, tb,
                     f1T, f1_b, f2T, f2_b, f3T, f3_b, outp);
}

// Round 11
// 1194.793 us; speedup vs baseline: 1.0979x; 1.0010x over previous
//
#include <hip/hip_runtime.h>
#include <math.h>

#define BB 32
#define HH_ 128
#define WW_ 256

typedef _Float16 f16_t;
typedef _Float16 half8 __attribute__((ext_vector_type(8)));
typedef _Float16 half4 __attribute__((ext_vector_type(4)));
typedef _Float16 half2v __attribute__((ext_vector_type(2)));
typedef float floatx4 __attribute__((ext_vector_type(4)));

// Branch-free fast gelu via A-S 7.1.28: 1-erf(t) = (1+a1 t+...+a6 t^6)^-16,
// |err| <= 3e-7. ONE quarter-rate op (rcp) vs 7.1.26's two (rcp+exp).
// gelu(v) = relu(v) - 0.5|v| * (1 - erf(|v|/sqrt2)).
__device__ __forceinline__ float gelu_f(float v){
  float t = __builtin_fabsf(v) * 0.70710678118654752f;
  float q = __builtin_fmaf(0.0000430638f, t, 0.0002765672f);
  q = __builtin_fmaf(q, t, 0.0001520143f);
  q = __builtin_fmaf(q, t, 0.0092705272f);
  q = __builtin_fmaf(q, t, 0.0422820123f);
  q = __builtin_fmaf(q, t, 0.0705230784f);
  q = __builtin_fmaf(q, t, 1.0f);
  float q2 = q*q, q4 = q2*q2, q8 = q4*q4;
  float q16 = q8*q8;
  float r = __builtin_amdgcn_rcpf(q16);          // = 1 - erf(t)
  float h = 0.5f * __builtin_fabsf(v);
  return __builtin_fmaf(-h, r, fmaxf(v, 0.f));
}

// Exact-reduced DFT twiddle: angle = sgn * 2*pi * (prod mod N) / N.
__device__ __forceinline__ float2 twiddle(int prod, int N, float sgn){
  int m = prod & (N - 1);
  float a = sgn * (6.2831853071795864769f / (float)N) * (float)m;
  return make_float2(cosf(a), sinf(a));
}

__global__ void k_diag(float* out, float v){ out[threadIdx.x] = v; }

// ---- merged prep: [0,113) tables+head-f16; [113,169) wprep;
//      [169,937) mixprep; [937,1001) twA; [1001,1009) ext-MLP g vector -------
__global__ __launch_bounds__(256) void k_prep(
      float* gg, float2* thf, float2* thi, f16_t* twzh,
      const float* __restrict__ f1_w, const float* __restrict__ f2_w,
      const float* __restrict__ f3_w, f16_t* f1T, f16_t* f2T, f16_t* f3T,
      const float* __restrict__ tw, f16_t* __restrict__ wT,
      const float* __restrict__ w1r, const float* __restrict__ w1i,
      const float* __restrict__ w2r, const float* __restrict__ w2i,
      float2* __restrict__ wmix, f16_t* __restrict__ twA,
      const float* __restrict__ ext, const float* __restrict__ day_emb,
      const float* __restrict__ hour_emb, const float* __restrict__ e1_w,
      const float* __restrict__ e1_b){
  __shared__ __align__(16) char smp[53248];
  int blk = blockIdx.x, tid = threadIdx.x;
  if (blk < 113){
    int t = blk*256 + tid;
    if (t < 3072){
      // spare slot
    } else if (t < 6144){                // forward h-DFT: [h][j]
      int f = t-3072; int h = f/24, j = f%24;
      int kx = (j<12)? j : j+104;
      thf[f] = twiddle(h*kx, 128, -1.f);
    } else if (t < 9216){                // inverse h (includes 1/128)
      int f = t-6144; int h = f/24, j = f%24;
      int kx = (j<12)? j : j+104;
      float2 c = twiddle(h*kx, 128, 1.f);
      thi[f] = make_float2(c.x*0.0078125f, c.y*0.0078125f);
    } else if (t < 12288){               // inverse w (c2r) coefs, f16
      int f = t-9216; int w = f/12, ky = f%12;
      float2 c = twiddle(w*ky, 256, 1.f);
      float s = (ky==0)? 0.00390625f : 0.0078125f;   // (1 or 2)/256
      twzh[w*32 + ky]      = (f16_t)( s*c.x);
      twzh[w*32 + 12 + ky] = (f16_t)(-s*c.y);
      if (ky < 8) twzh[w*32 + 24 + ky] = (f16_t)0.f;
    } else {
      int t2 = t - 12288;                // head weights -> f16
      if (t2 < 8192) f1T[t2] = (f16_t)f1_w[t2];
      else if (t2 < 16384) f2T[t2-8192] = (f16_t)f2_w[t2-8192];
      else if (t2 < 16512) f3T[t2-16384] = (f16_t)f3_w[t2-16384];
    }
  } else if (blk < 169){                 // conv weight transpose via LDS
    float* s = (float*)smp;              // [o16][c][tap]
    int b2 = blk - 113;
    int og = b2 & 3, tt = b2 >> 2;
    const float* src = tw + (long)tt*36864 + og*9216;
    for (int f = tid; f < 9216; f += 256) s[f] = src[f];
    __syncthreads();
    for (int f = tid; f < 9216; f += 256){
      int c = f & 63; int r = f >> 6;
      int o16 = r % 16, tap = r / 16;
      float v = s[(o16*64 + c)*9 + tap];
      wT[(((long)tt*9 + tap)*64 + og*16 + o16)*64 + c] = (f16_t)v;
    }
  } else if (blk < 937){                 // spectral weight transpose via LDS
    float* sr = (float*)smp;             // 6656 f
    float* si = (float*)(smp + 26624);   // 6656 f
    int b2 = blk - 169;                  // < 768
    int ig  = b2 & 7;
    int kx  = (b2 >> 3) % 12;
    int sel = (b2 / 96) & 1;
    int l   = b2 / 192;
    const float* wr = sel ? w2r : w1r;
    const float* wi = sel ? w2i : w1i;
    for (int f = tid; f < 6144; f += 256){
      int i8 = f / 768; int rem = f % 768;
      int o = rem / 12, ky = rem % 12;
      long addr = (((long)l*64 + ig*8 + i8)*64 + o)*144 + kx*12 + ky;
      sr[(i8*64 + o)*13 + ky] = wr[addr];
      si[(i8*64 + o)*13 + ky] = wi[addr];
    }
    __syncthreads();
    int j = sel ? (kx + 12) : kx;
    for (int f = tid; f < 6144; f += 256){
      int o = f & 63; int r = f >> 6;
      int ky = r % 12, i8 = r / 12;
      int sidx = (i8*64 + o)*13 + ky;
      wmix[(((long)l*288 + j*12 + ky))*4096 + (ig*8 + i8)*64 + o] =
          make_float2(sr[sidx], si[sidx]);
    }
  } else if (blk < 1001){                // twA[half][hl][32 m][128 k] f16
    int t = (blk - 937)*256 + tid;       // < 16384
    int halfi = t >> 13, r = t & 8191;
    int hl = r >> 12, r2 = r & 4095;
    int m = r2 >> 7, k = r2 & 127;
    f16_t v = (f16_t)0.f;
    if (m < 24){
      int ky = m >> 1, ri = m & 1;
      int w = halfi*128 + k;
      float2 c = twiddle(w*ky, 256, -1.f);
      float t32 = ri ? c.y : c.x;
      f16_t hi = (f16_t)t32;
      v = hl ? (f16_t)(t32 - (float)hi) : hi;
    }
    twA[t] = v;
  } else {                               // ext MLP g: gg[32 b][64 j]
    int b2 = blk - 1001;                 // 0..7
    int bloc = tid >> 6, j = tid & 63;
    int b = b2*4 + bloc;
    const float* e = ext + b*6;
    float emb[6];
    emb[0] = e[0];
    int d  = (int)e[2];
    emb[1] = day_emb[d*2];  emb[2] = day_emb[d*2+1];
    int hr = (int)e[3];
    emb[3] = hour_emb[hr*3]; emb[4] = hour_emb[hr*3+1]; emb[5] = hour_emb[hr*3+2];
    float acc = e1_b[j];
    #pragma unroll
    for (int k = 0; k < 6; k++) acc += emb[k]*e1_w[j*6+k];
    gg[b*64 + j] = gelu_f(acc);
  }
}

// ---- gate precompute: gate[b][hw] = gelu(g[b] . e2_w[hw] + e2_b[hw]) --------
__global__ __launch_bounds__(256) void k_gate(const float* __restrict__ gg,
      const float* __restrict__ e2_w, const float* __restrict__ e2_b,
      float* __restrict__ gate){
  __shared__ float gs[2048];
  int tid = threadIdx.x;
  for (int f = tid; f < 2048; f += 256) gs[f] = gg[f];
  __syncthreads();
  long hw = (long)blockIdx.x*256 + tid;
  const float4* wrow = (const float4*)(e2_w + hw*64);
  float4 w[16];
  #pragma unroll
  for (int k = 0; k < 16; k++) w[k] = wrow[k];
  float eb2 = e2_b[hw];
  for (int b = 0; b < 32; b++){
    const float* g = gs + b*64;
    float acc = eb2;
    #pragma unroll
    for (int k = 0; k < 16; k++){
      float4 v = w[k];
      acc += v.x*g[4*k] + v.y*g[4*k+1] + v.z*g[4*k+2] + v.w*g[4*k+3];
    }
    gate[(long)b*32768 + hw] = gelu_f(acc);
  }
}

// ---- encoder + layer-0 w-DFT (MFMA), block=(b,h) row; gate precomputed -----
__global__ __launch_bounds__(256) void k_gxdft(
      const float* __restrict__ gate, const float* __restrict__ inp,
      const float* __restrict__ enc_w, const float* __restrict__ enc_b,
      const f16_t* __restrict__ twA, f16_t* __restrict__ x,
      float2* __restrict__ fp0, float2* __restrict__ fp1){
  __shared__ __align__(16) char sm[41984];
  f16_t* Obt   = (f16_t*)sm;              // [64 c][274 w-pad]  35072 B
  float* gvs   = (float*)(sm + 35072);    // 256
  float4* ips  = (float4*)(sm + 36096);   // 256 float4
  float* ew    = (float*)(sm + 40448);    // 320
  float* eb    = (float*)(sm + 41728);    // 64
  int tid = threadIdx.x;
  int bh = blockIdx.x;                    // b*128 + h
  int b = bh >> 7, h = bh & 127;
  if (tid < 64) eb[tid] = enc_b[tid];
  for (int f = tid; f < 320; f += 256) ew[f] = enc_w[f];
  {                                        // gate load + input stage per pixel
    int px = tid;
    long hw = (long)h*256 + px;
    gvs[px] = gate[(long)b*32768 + hw];
    ips[px] = *(const float4*)(inp + ((long)b*32768 + hw)*4);
  }
  __syncthreads();
  int lane = tid & 63, wv = tid >> 6;
  {                                        // encoder: thread = (c, 64-px group)
    int c = lane, wg = wv;
    const float* wr2 = ew + c*5;
    float w0 = wr2[0], w1 = wr2[1], w2 = wr2[2], w3 = wr2[3], w4 = wr2[4];
    float ebc = eb[c];
    f16_t* xo = x + ((long)bh*256 + wg*64)*64 + c;
    #pragma unroll 2
    for (int g8 = 0; g8 < 8; g8++){
      half8 hv;
      #pragma unroll
      for (int e2 = 0; e2 < 8; e2++){
        int i = g8*8 + e2;
        float4 ip = ips[wg*64 + i];
        float gv = gvs[wg*64 + i];
        float v = ebc + ip.x*w0 + ip.y*w1 + ip.z*w2 + ip.w*w3 + gv*w4;
        f16_t hval = (f16_t)v;
        hv[e2] = hval;
        xo[i*64] = hval;                   // coalesced across lanes (same i)
      }
      *(half8*)(Obt + c*274 + wg*64 + g8*8) = hv;
    }
  }
  __syncthreads();                         // Obt ready
  int n15 = lane & 15, quad = lane >> 4;
  int n = wv*16 + n15;
  #pragma unroll
  for (int half = 0; half < 2; half++){
    half8 bfr2[4];
    #pragma unroll
    for (int ks = 0; ks < 4; ks++)
      bfr2[ks] = *(const half8*)(Obt + n*274 + half*128 + ks*32 + quad*8);
    floatx4 dacc[2];
    dacc[0] = (floatx4){0.f,0.f,0.f,0.f};
    dacc[1] = (floatx4){0.f,0.f,0.f,0.f};
    #pragma unroll
    for (int hl = 0; hl < 2; hl++){
      #pragma unroll
      for (int mt = 0; mt < 2; mt++){
        #pragma unroll
        for (int ks = 0; ks < 4; ks++){
          half8 a = *(const half8*)(twA + half*8192 + hl*4096
                                    + (mt*16 + n15)*128 + ks*32 + quad*8);
          dacc[mt] = __builtin_amdgcn_mfma_f32_16x16x32_f16(a, bfr2[ks],
                                                            dacc[mt], 0,0,0);
        }
      }
    }
    float2* dst = half ? fp1 : fp0;
    #pragma unroll
    for (int mt = 0; mt < 2; mt++){
      int m0 = mt*16 + quad*4;
      if (m0 < 24){
        int ky0 = m0 >> 1;
        dst[(long)bh*768 + ky0*64 + n]     = make_float2(dacc[mt][0], dacc[mt][1]);
        dst[(long)bh*768 + (ky0+1)*64 + n] = make_float2(dacc[mt][2], dacc[mt][3]);
      }
    }
  }
}

// ---- FUSED spectral chain: dft_h + mode-mix + ifft_h, block=(b,ky) ---------
__global__ __launch_bounds__(256) void k_spec(const float2* __restrict__ s0,
      const float2* __restrict__ s1, int dual, const float2* __restrict__ thf_g,
      const float2* __restrict__ thi_g, const float2* __restrict__ wmix,
      int layer, float2* __restrict__ zi){
  __shared__ __align__(16) char sm[40960];
  float2* th  = (float2*)sm;            // 3072 f2: thf (A) then thi (C)
  float2* xch = (float2*)(sm + 24576);  // 2048 f2 staging (A)
  float2* mixL= (float2*)(sm + 24576);  // [24 j][64 o] (B->C), aliases xch
  int tid = threadIdx.x;
  int b = blockIdx.x / 12, ky = blockIdx.x % 12;
  int wv = tid >> 6, lane = tid & 63;
  for (int f = tid; f < 3072; f += 256) th[f] = thf_g[f];
  // Stage A: h-DFT. acc[q] = xft[j=q*4+wv][c=lane]
  float2 acc[6];
  #pragma unroll
  for (int q = 0; q < 6; q++) acc[q] = make_float2(0.f, 0.f);
  long base = (long)b*98304 + ky*64;
  for (int ch = 0; ch < 4; ch++){
    __syncthreads();
    for (int f = tid; f < 2048; f += 256){
      int hh = f >> 6, c = f & 63;
      long idx = base + (long)(ch*32 + hh)*768 + c;
      float2 v = s0[idx];
      if (dual){ float2 u = s1[idx]; v.x += u.x; v.y += u.y; }
      xch[f] = v;
    }
    __syncthreads();
    for (int hh = 0; hh < 32; hh++){
      float2 v = xch[hh*64 + lane];
      int hg = ch*32 + hh;
      #pragma unroll
      for (int q = 0; q < 6; q++){
        float2 t = th[hg*24 + q*4 + wv];
        acc[q].x += t.x*v.x - t.y*v.y;
        acc[q].y += t.x*v.y + t.y*v.x;
      }
    }
  }
  __syncthreads();                      // A done: xch & thf dead after here
  for (int f = tid; f < 3072; f += 256) th[f] = thi_g[f];   // stage thi
  // Stage B: mode-mix, register-resident via shfl
  float2 mout[6];
  #pragma unroll
  for (int q = 0; q < 6; q++){
    int j = q*4 + wv;
    const float2* wj = wmix + (((long)layer*288 + j*12 + ky))*4096;
    float re = 0.f, im = 0.f;
    #pragma unroll 8
    for (int i = 0; i < 64; i++){
      float vr = __shfl(acc[q].x, i);
      float vi = __shfl(acc[q].y, i);
      float2 ww = wj[i*64 + lane];
      re += vr*ww.x - vi*ww.y;
      im += vr*ww.y + vi*ww.x;
    }
    mout[q] = make_float2(re, im);
  }
  #pragma unroll
  for (int q = 0; q < 6; q++) mixL[(q*4 + wv)*64 + lane] = mout[q];
  __syncthreads();                      // mixL + thi ready
  // Stage C: inverse h-DFT
  float2 cr[24];
  #pragma unroll
  for (int j = 0; j < 24; j++) cr[j] = mixL[j*64 + lane];
  for (int qq = 0; qq < 32; qq++){
    int h = qq*4 + wv;
    float re = 0.f, im = 0.f;
    #pragma unroll
    for (int j = 0; j < 24; j++){
      float2 t = th[h*24 + j];
      re += t.x*cr[j].x - t.y*cr[j].y;
      im += t.x*cr[j].y + t.y*cr[j].x;
    }
    zi[((long)b*128 + h)*768 + ky*64 + lane] = make_float2(re, im);
  }
}

// ------- MFMA: inverse-w + skip + bias + (gelu), in place on x,
//         fused next-layer partial w-DFT via MFMA (twA hi/lo) ----------------
// dodft B-fragments via intra-wave __shfl of the packed epilogue values.
__global__ __launch_bounds__(256) void k_iw_mfma(f16_t* __restrict__ x,
      const float2* __restrict__ zi, const float* __restrict__ ws_w,
      const float* __restrict__ ws_b, const f16_t* __restrict__ twzh,
      const f16_t* __restrict__ twA, float2* __restrict__ fp0,
      float2* __restrict__ fp1, int layer, int act, int dodft){
  __shared__ __align__(16) char sm[28672];
  f16_t* A1  = (f16_t*)sm;                  // [128 px][72] x channels
  f16_t* Bzh = (f16_t*)(sm + 18432);        // [64 o][40]
  f16_t* Bzl = (f16_t*)(sm + 23552);        // [64 o][40]
  int tid = threadIdx.x;
  int blk = blockIdx.x;
  int half = blk & 1;
  long bh = blk >> 1;                       // b*128 + h
  int w0 = half*128;
  const f16_t* xrow = x + (bh*256 + w0)*64;
  for (int f = tid; f < 1024; f += 256){    // A1: 128 px x 8 chunks, 16B
    int px = f >> 3, c8 = f & 7;
    *(float4*)(A1 + px*72 + c8*8) = *(const float4*)(xrow + px*64 + c8*8);
  }
  const float2* zrow = zi + bh*768;
  for (int f = tid; f < 768; f += 256){     // z hi/lo split
    int o = f & 63, ky = f >> 6;
    float2 v = zrow[ky*64 + o];
    f16_t hr = (f16_t)v.x; f16_t hi_ = (f16_t)v.y;
    Bzh[o*40 + ky]      = hr;
    Bzh[o*40 + 12 + ky] = hi_;
    Bzl[o*40 + ky]      = (f16_t)(v.x - (float)hr);
    Bzl[o*40 + 12 + ky] = (f16_t)(v.y - (float)hi_);
  }
  if (tid < 64){                            // zero cols 24..31 (read by quad 3)
    float4 z4 = {0.f,0.f,0.f,0.f};
    *(float4*)(Bzh + tid*40 + 24) = z4;
    *(float4*)(Bzl + tid*40 + 24) = z4;
  }
  __syncthreads();                          // the ONLY barrier
  int lane = tid & 63, wv = tid >> 6;
  int n15 = lane & 15, quad = lane >> 4;
  int n = wv*16 + n15;
  // B fragments: ws from global f32 (L2-hot, 16KB/layer), z from LDS
  half8 bws[2];
  {
    const float* wsl = ws_w + ((long)layer*64 + n)*64;
    #pragma unroll
    for (int kc = 0; kc < 2; kc++){
      float4 u0 = *(const float4*)(wsl + kc*32 + quad*8);
      float4 u1 = *(const float4*)(wsl + kc*32 + quad*8 + 4);
      half8 hb;
      hb[0]=(f16_t)u0.x; hb[1]=(f16_t)u0.y; hb[2]=(f16_t)u0.z; hb[3]=(f16_t)u0.w;
      hb[4]=(f16_t)u1.x; hb[5]=(f16_t)u1.y; hb[6]=(f16_t)u1.z; hb[7]=(f16_t)u1.w;
      bws[kc] = hb;
    }
  }
  float bias = ws_b[layer*64 + n];
  half8 bzh = *(const half8*)(Bzh + n*40 + quad*8);
  half8 bzl = *(const half8*)(Bzl + n*40 + quad*8);
  floatx4 acc[8];
  #pragma unroll
  for (int mt = 0; mt < 8; mt++){
    floatx4 c = {bias, bias, bias, bias};   // bias folded into accumulator
    half8 ax0 = *(const half8*)(A1 + (mt*16 + n15)*72 + quad*8);
    half8 ax1 = *(const half8*)(A1 + (mt*16 + n15)*72 + 32 + quad*8);
    half8 atw = *(const half8*)(twzh + (w0 + mt*16 + n15)*32 + quad*8);
    c = __builtin_amdgcn_mfma_f32_16x16x32_f16(ax0, bws[0], c, 0,0,0);
    c = __builtin_amdgcn_mfma_f32_16x16x32_f16(ax1, bws[1], c, 0,0,0);
    c = __builtin_amdgcn_mfma_f32_16x16x32_f16(atw, bzh,    c, 0,0,0);
    c = __builtin_amdgcn_mfma_f32_16x16x32_f16(atw, bzl,    c, 0,0,0);
    acc[mt] = c;
  }
  // epilogue: gelu + coalesced scalar store + pack for shfl exchange
  f16_t* xo = x + (bh*256 + w0)*64;
  uint2 pk[8];
  #pragma unroll
  for (int mt = 0; mt < 8; mt++){
    half4 hv;
    #pragma unroll
    for (int r = 0; r < 4; r++){
      float v = acc[mt][r];
      if (act) v = gelu_f(v);
      hv[r] = (f16_t)v;
      xo[(mt*16 + quad*4 + r)*64 + n] = hv[r];
    }
    pk[mt] = __builtin_bit_cast(uint2, hv);
  }
  if (dodft){                                // next-layer w-DFT, B via shfl
    int qhalf = quad >> 1;
    int srcA = ((quad & 1) << 5) + n15;       // lane of quad_src = 2*(quad&1)
    int srcB = srcA + 16;
    half8 bfr2[4];
    #pragma unroll
    for (int ks = 0; ks < 4; ks++){
      uint2 lo  = pk[2*ks];
      uint2 hi2 = pk[2*ks + 1];
      unsigned w0a_l = (unsigned)__shfl((int)lo.x,  srcA, 64);
      unsigned w1a_l = (unsigned)__shfl((int)lo.y,  srcA, 64);
      unsigned w0a_h = (unsigned)__shfl((int)hi2.x, srcA, 64);
      unsigned w1a_h = (unsigned)__shfl((int)hi2.y, srcA, 64);
      unsigned w0b_l = (unsigned)__shfl((int)lo.x,  srcB, 64);
      unsigned w1b_l = (unsigned)__shfl((int)lo.y,  srcB, 64);
      unsigned w0b_h = (unsigned)__shfl((int)hi2.x, srcB, 64);
      unsigned w1b_h = (unsigned)__shfl((int)hi2.y, srcB, 64);
      uint4 u;
      u.x = qhalf ? w0a_h : w0a_l;
      u.y = qhalf ? w1a_h : w1a_l;
      u.z = qhalf ? w0b_h : w0b_l;
      u.w = qhalf ? w1b_h : w1b_l;
      bfr2[ks] = __builtin_bit_cast(half8, u);
    }
    floatx4 dacc[2];
    dacc[0] = (floatx4){0.f,0.f,0.f,0.f};
    dacc[1] = (floatx4){0.f,0.f,0.f,0.f};
    #pragma unroll
    for (int hl = 0; hl < 2; hl++){
      #pragma unroll
      for (int mt = 0; mt < 2; mt++){
        #pragma unroll
        for (int ks = 0; ks < 4; ks++){
          half8 a = *(const half8*)(twA + half*8192 + hl*4096
                                    + (mt*16 + n15)*128 + ks*32 + quad*8);
          dacc[mt] = __builtin_amdgcn_mfma_f32_16x16x32_f16(a, bfr2[ks],
                                                            dacc[mt], 0,0,0);
        }
      }
    }
    float2* dst = half ? fp1 : fp0;
    #pragma unroll
    for (int mt = 0; mt < 2; mt++){
      int m0 = mt*16 + quad*4;
      if (m0 < 24){
        int ky0 = m0 >> 1;
        dst[bh*768 + ky0*64 + n]     = make_float2(dacc[mt][0], dacc[mt][1]);
        dst[bh*768 + (ky0+1)*64 + n] = make_float2(dacc[mt][2], dacc[mt][3]);
      }
    }
  }
}

// ------- MFMA conv 3x3 (per-batch weights) + gelu + head, fused; 64-px tiles -
__global__ __launch_bounds__(256) void k_conv_head(const f16_t* __restrict__ x,
      const float* __restrict__ ext, const f16_t* __restrict__ wT,
      const float* __restrict__ tb, const f16_t* __restrict__ f1T,
      const float* __restrict__ f1_b, const f16_t* __restrict__ f2T,
      const float* __restrict__ f2_b, const f16_t* __restrict__ f3T,
      const float* __restrict__ f3_b, float* __restrict__ out){
  __shared__ __align__(16) char sm[29824];
  f16_t* hf   = (f16_t*)sm;                 // [64][72]   (phase: hf -> z1 read)
  f16_t* z1   = (f16_t*)(sm + 9216);        // [64][136]
  f16_t* z2   = (f16_t*)sm;                 // [64][72]   aliases hf (hf dead)
  float* tbs  = (float*)(sm + 28512);       // above xt halo region
  float* f1bs = (float*)(sm + 28768);
  float* f2bs = (float*)(sm + 29280);
  f16_t* f3s  = (f16_t*)(sm + 29536);
  float* f3bs = (float*)(sm + 29792);
  f16_t* xt   = (f16_t*)sm;                 // [3][66][72] (conv phase) 28512 B

  int tid = threadIdx.x;
  int blk = blockIdx.x;
  int wc = blk & 3, h = (blk >> 2) & 127, b = blk >> 9;
  int w0 = wc*64;
  int t_idx = (int)ext[b*6+3] - 5;

  if (tid < 64) tbs[tid] = tb[t_idx*64 + tid];
  else if (tid < 192) f1bs[tid-64] = f1_b[tid-64];
  else f2bs[tid-192] = f2_b[tid-192];
  if (tid < 128) f3s[tid] = f3T[tid];
  if (tid < 2) f3bs[tid] = f3_b[tid];

  // main interior 64 px: pow2 indexing, only h-bounds check
  for (int f = tid; f < 1536; f += 256){
    int c8 = f & 7, px = (f >> 3) & 63, dy = f >> 9;
    int hh = h - 1 + dy;
    float4 v = {0.f,0.f,0.f,0.f};
    if (hh >= 0 && hh < HH_)
      v = *(const float4*)(x + (((long)b*HH_ + hh)*WW_ + w0 + px)*64 + c8*8);
    *(float4*)(xt + (dy*66 + px + 1)*72 + c8*8) = v;
  }
  if (tid < 48){                            // halo columns pxl = 0 and 65
    int c8 = tid & 7, r = tid >> 3;         // r: 0..5
    int dy = r >> 1, side = r & 1;
    int pxl = side ? 65 : 0;
    int hh = h - 1 + dy, wg = w0 - 1 + pxl;
    float4 v = {0.f,0.f,0.f,0.f};
    if (hh >= 0 && hh < HH_ && wg >= 0 && wg < WW_)
      v = *(const float4*)(x + (((long)b*HH_ + hh)*WW_ + wg)*64 + c8*8);
    *(float4*)(xt + (dy*66 + pxl)*72 + c8*8) = v;
  }
  __syncthreads();

  int lane = tid & 63, wv = tid >> 6;
  int n15 = lane & 15, quad = lane >> 4;
  int n = wv*16 + n15;

  floatx4 acc[4];
  {
    float bias0 = tbs[n];                   // per-thread const -> acc init
    #pragma unroll
    for (int mt = 0; mt < 4; mt++) acc[mt] = (floatx4){bias0,bias0,bias0,bias0};
  }
  const f16_t* wTt = wT + (long)t_idx*36864;
  for (int tap = 0; tap < 9; tap++){
    int dy = tap/3, dx = tap%3;
    const f16_t* wrow = wTt + (tap*64 + wv*16 + n15)*64;
    #pragma unroll
    for (int kc = 0; kc < 2; kc++){
      half8 bfrag = *(const half8*)(wrow + kc*32 + quad*8);
      #pragma unroll
      for (int mt = 0; mt < 4; mt++){
        int p = mt*16 + n15 + dx;
        half8 a = *(const half8*)(xt + (dy*66 + p)*72 + kc*32 + quad*8);
        acc[mt] = __builtin_amdgcn_mfma_f32_16x16x32_f16(a, bfrag, acc[mt], 0,0,0);
      }
    }
  }
  __syncthreads();                           // xt dead
  {
    #pragma unroll
    for (int mt = 0; mt < 4; mt++){
      #pragma unroll
      for (int r = 0; r < 4; r++){
        int m = mt*16 + quad*4 + r;
        hf[m*72 + n] = (f16_t)gelu_f(acc[mt][r]);
      }
    }
  }
  __syncthreads();
  // z1 = gelu(hf . f1^T + f1_b): M=64 N=128 K=64
  #pragma unroll
  for (int nt = 0; nt < 2; nt++){
    int n1 = wv*32 + nt*16 + n15;
    float bias = f1bs[n1];
    half8 bf0 = *(const half8*)(f1T + n1*64 + quad*8);
    half8 bf1 = *(const half8*)(f1T + n1*64 + 32 + quad*8);
    #pragma unroll
    for (int mt = 0; mt < 4; mt++){
      floatx4 c = {bias, bias, bias, bias};
      half8 a0 = *(const half8*)(hf + (mt*16 + n15)*72 + quad*8);
      half8 a1 = *(const half8*)(hf + (mt*16 + n15)*72 + 32 + quad*8);
      c = __builtin_amdgcn_mfma_f32_16x16x32_f16(a0, bf0, c, 0,0,0);
      c = __builtin_amdgcn_mfma_f32_16x16x32_f16(a1, bf1, c, 0,0,0);
      #pragma unroll
      for (int r = 0; r < 4; r++){
        int m = mt*16 + quad*4 + r;
        z1[m*136 + n1] = (f16_t)gelu_f(c[r]);
      }
    }
  }
  __syncthreads();
  // z2 = gelu(z1 . f2^T + f2_b): M=64 N=64 K=128  (z2 overwrites dead hf)
  {
    float bias = f2bs[n];
    half8 bf[4];
    #pragma unroll
    for (int kc = 0; kc < 4; kc++)
      bf[kc] = *(const half8*)(f2T + n*128 + kc*32 + quad*8);
    #pragma unroll
    for (int mt = 0; mt < 4; mt++){
      floatx4 c = {bias, bias, bias, bias};
      #pragma unroll
      for (int kc = 0; kc < 4; kc++){
        half8 a = *(const half8*)(z1 + (mt*16 + n15)*136 + kc*32 + quad*8);
        c = __builtin_amdgcn_mfma_f32_16x16x32_f16(a, bf[kc], c, 0,0,0);
      }
      #pragma unroll
      for (int r = 0; r < 4; r++){
        int m = mt*16 + quad*4 + r;
        z2[m*72 + n] = (f16_t)gelu_f(c[r]);
      }
    }
  }
  __syncthreads();
  // f3: out[px][0..1]
  if (tid < 128){
    int px = tid >> 1, oo = tid & 1;
    const f16_t* zr = z2 + px*72;
    const f16_t* fr = f3s + oo*64;
    float a = f3bs[oo];
    #pragma unroll
    for (int g = 0; g < 8; g++){
      half8 zv = *(const half8*)(zr + g*8);
      half8 wv2 = *(const half8*)(fr + g*8);
#if __has_builtin(__builtin_amdgcn_fdot2)
      #pragma unroll
      for (int q = 0; q < 4; q++){
        half2v za = {zv[2*q], zv[2*q+1]};
        half2v wa = {wv2[2*q], wv2[2*q+1]};
        a = __builtin_amdgcn_fdot2(za, wa, a, false);
      }
#else
      #pragma unroll
      for (int q = 0; q < 8; q++) a += (float)zv[q]*(float)wv2[q];
#endif
    }
    out[(((long)b*HH_ + h)*WW_ + w0 + px)*2 + oo] = a;
  }
}

extern "C" void kernel_launch(void* const* d_in, const int* in_sizes, int n_in,
                              void* d_out, int out_size, void* d_ws, size_t ws_size,
                              hipStream_t stream){
  const float* inp     = (const float*)d_in[0];
  const float* ext     = (const float*)d_in[1];
  const float* enc_w   = (const float*)d_in[2];
  const float* enc_b   = (const float*)d_in[3];
  const float* w1r     = (const float*)d_in[4];
  const float* w1i     = (const float*)d_in[5];
  const float* w2r     = (const float*)d_in[6];
  const float* w2i     = (const float*)d_in[7];
  const float* ws_w    = (const float*)d_in[8];
  const float* ws_b    = (const float*)d_in[9];
  const float* day_emb = (const float*)d_in[10];
  const float* hour_emb= (const float*)d_in[11];
  const float* e1_w    = (const float*)d_in[12];
  const float* e1_b    = (const float*)d_in[13];
  const float* e2_w    = (const float*)d_in[14];
  const float* e2_b    = (const float*)d_in[15];
  const float* tw      = (const float*)d_in[16];
  const float* tb      = (const float*)d_in[17];
  const float* f1_w    = (const float*)d_in[18];
  const float* f1_b    = (const float*)d_in[19];
  const float* f2_w    = (const float*)d_in[20];
  const float* f2_b    = (const float*)d_in[21];
  const float* f3_w    = (const float*)d_in[22];
  const float* f3_b    = (const float*)d_in[23];
  float* outp = (float*)d_out;

  const size_t need = 248652032;
  if (ws_size < need){
    k_diag<<<dim3(1), dim3(64), 0, stream>>>(outp, (float)(ws_size >> 20));
    return;
  }
  char* p = (char*)d_ws;
  f16_t*  x    = (f16_t*)(p);                    // 134217728 B
  float2* fp0  = (float2*)(p + 134217728);       // 25165824 B
  float2* fp1  = (float2*)(p + 159383552);       // 25165824 B
  float2* zi   = (float2*)(p + 184549376);       // 25165824 B
  float*  gate = (float*)(p + 184549376);        // 4 MB, aliases zi (dead till spec)
  float*  gg   = (float*)(p + 209715200);        // 8 KB, in old twf region
  float2* thf  = (float2*)(p + 209739776);       // 24576 B
  float2* thi  = (float2*)(p + 209764352);       // 24576 B
  f16_t*  twzh = (f16_t*)(p + 209788928);        // 16384 B
  f16_t*  wT   = (f16_t*)(p + 209805312);        // 1032192 B
  f16_t*  f1T  = (f16_t*)(p + 210837504);        // 16384 B
  f16_t*  f2T  = (f16_t*)(p + 210853888);        // 16384 B
  f16_t*  f3T  = (f16_t*)(p + 210870272);        // 256 B
  float2* wmix = (float2*)(p + 210870528);       // 37748736 B
  f16_t*  twA  = (f16_t*)(p + 248619264);        // 32768 B

  k_prep<<<dim3(1009), dim3(256), 0, stream>>>(gg, thf, thi, twzh,
      f1_w, f2_w, f3_w, f1T, f2T, f3T, tw, wT, w1r, w1i, w2r, w2i, wmix, twA,
      ext, day_emb, hour_emb, e1_w, e1_b);
  k_gate<<<dim3(128), dim3(256), 0, stream>>>(gg, e2_w, e2_b, gate);
  k_gxdft<<<dim3(4096), dim3(256), 0, stream>>>(gate, inp, enc_w, enc_b,
                                                twA, x, fp0, fp1);
  for (int l = 0; l < 4; l++){
    k_spec<<<dim3(384), dim3(256), 0, stream>>>(fp0, fp1, 1,
                                                thf, thi, wmix, l, zi);
    k_iw_mfma<<<dim3(8192), dim3(256), 0, stream>>>(x, zi, ws_w, ws_b, twzh,
                       twA, fp0, fp1, l, (l < 3) ? 1 : 0, (l < 3) ? 1 : 0);
  }
  k_conv_head<<<dim3(16384), dim3(256), 0, stream>>>(x, ext, wT, tb,
                     f1T, f1_b, f2T, f2_b, f3T, f3_b, outp);
}